// Round 3
// baseline (1012.145 us; speedup 1.0000x reference)
//
#include <hip/hip_runtime.h>

// GraphAttention (e3nn-style) on MI355X — Round 7: i-split, 1 edge/thread.
// Round-6 post-mortem: 2 edges/thread duplicated hk (64 regs) + accumulators
// (~190 live floats) -> VGPR maxed at 256, scratch spill (FETCH 275MB/WRITE
// 255MB of spill traffic), 338us. The i-split itself was correct (0 bank
// conflicts, passed). Fix: 1 edge/thread (hk 32 + acc 32 + temps ~ 110 VGPR,
// no spill), EPB=64 -> 1563 blocks, ~6 blocks/CU, 3-4 waves/SIMD.
// __launch_bounds__(256,3) caps VGPR at 170 as spill insurance.
//
// Dims: M0=16 M1=8 Q0=8 Q1=4 O0=16 O1=8 EDGE_BASIS=16 HIDDEN=32
// TPK [32][320]: w1[0,128) w2[128,192) w3[192,256) w4[256,288) w5[288,320)
// TPV [32][640]: w1[0,256) w2[256,384) w3[384,512) w4[512,576) w5[576,640)
//
// Pipeline: node_pre | count_edges | scan | edge_k | edge_v_a | edge_v_b | node_reduce
// ws (4B units): qd[N*20] | cnt[N] | start[N+1] | cursor[N] | flag | pad |
//                exbuf[E] | sabuf[E] | posbuf[E] | vbuf[E*40]

#define BS 256           // threads per block (edge kernels)
#define EPB 64           // edges per block: 4 waves x 16 q-lanes x 1 edge

__device__ __forceinline__ float silu_f(float x) {
    return x * (1.0f / (1.0f + __expf(-x)));
}
__device__ __forceinline__ unsigned short f2b(float f) {   // f32 -> bf16 (RNE)
    unsigned u = __float_as_uint(f);
    u += 0x7fffu + ((u >> 16) & 1u);
    return (unsigned short)(u >> 16);
}
__device__ __forceinline__ float bl(unsigned u) {          // low bf16 -> f32
    return __uint_as_float(u << 16);
}
__device__ __forceinline__ float bh(unsigned u) {          // high bf16 -> f32
    return __uint_as_float(u & 0xffff0000u);
}
__device__ __forceinline__ unsigned pk2(float a, float b) { // pack 2 bf16
    return (unsigned)f2b(a) | ((unsigned)f2b(b) << 16);
}
__device__ __forceinline__ void up8(const uint4 a, float* w) {
    w[0] = bl(a.x); w[1] = bh(a.x); w[2] = bl(a.y); w[3] = bh(a.y);
    w[4] = bl(a.z); w[5] = bh(a.z); w[6] = bl(a.w); w[7] = bh(a.w);
}
__device__ __forceinline__ float wred4(float v) {          // sum over 4 p-groups
    v += __shfl_xor(v, 16);
    v += __shfl_xor(v, 32);
    return v;
}

__global__ __launch_bounds__(256) void node_pre(
    const float* __restrict__ node_ft,
    const int*   __restrict__ ei,
    const float* __restrict__ w_q_s, const float* __restrict__ w_q_v,
    const float* __restrict__ wdot_s, const float* __restrict__ wdot_v,
    float* __restrict__ qd, int* __restrict__ cnt, int* __restrict__ flag,
    int N, int E)
{
    const int n = blockIdx.x * blockDim.x + threadIdx.x;
    if (n == 0) {
        int acc = 0;
        const int kmax = (E < 64) ? E : 64;
        for (int k = 0; k < kmax; ++k) acc |= ei[2*k + 1];
        *flag = (acc == 0) ? 1 : 0;   // int64 layout => odd words all zero
    }
    if (n >= N) return;
    cnt[n] = 0;

    const float* nf = node_ft + (size_t)n * 40;
    float xs[16];
#pragma unroll
    for (int i = 0; i < 16; ++i) xs[i] = nf[i];
    float q[8];
#pragma unroll
    for (int o = 0; o < 8; ++o) {
        float a = 0.f;
#pragma unroll
        for (int i = 0; i < 16; ++i) a += xs[i] * w_q_s[i*8 + o];
        q[o] = a * 0.25f;
    }
    float* qdn = qd + (size_t)n * 20;
#pragma unroll
    for (int j = 0; j < 8; ++j) {
        float a = 0.f;
#pragma unroll
        for (int i = 0; i < 8; ++i) a += q[i] * wdot_s[i*8 + j];
        qdn[j] = a;
    }
    float xv[8][3];
#pragma unroll
    for (int i = 0; i < 8; ++i)
#pragma unroll
        for (int c = 0; c < 3; ++c) xv[i][c] = nf[16 + i*3 + c];
    float qv[4][3];
#pragma unroll
    for (int o = 0; o < 4; ++o)
#pragma unroll
        for (int c = 0; c < 3; ++c) {
            float a = 0.f;
#pragma unroll
            for (int i = 0; i < 8; ++i) a += xv[i][c] * w_q_v[i*4 + o];
            qv[o][c] = a * 0.35355339059327379f;
        }
#pragma unroll
    for (int j = 0; j < 4; ++j)
#pragma unroll
        for (int c = 0; c < 3; ++c) {
            float a = 0.f;
#pragma unroll
            for (int i = 0; i < 4; ++i) a += qv[i][c] * wdot_v[i*4 + j];
            qdn[8 + j*3 + c] = a;
        }
}

__global__ __launch_bounds__(256) void count_edges(
    const int* __restrict__ ei, int* __restrict__ cnt,
    const int* __restrict__ flag, int E)
{
    const int e = blockIdx.x * blockDim.x + threadIdx.x;
    if (e >= E) return;
    const int is64 = *flag;
    const int rcv = is64 ? ei[2*(E + e)] : ei[E + e];
    atomicAdd(cnt + rcv, 1);
}

// 1 block, 1024 threads; shuffle-based scan (few barriers).
__global__ __launch_bounds__(1024) void scan_kernel(
    const int* __restrict__ cnt, int* __restrict__ start,
    int* __restrict__ cursor, int N)
{
    __shared__ int wsum[16];
    __shared__ int s_carry;
    const int tid = threadIdx.x, wave = tid >> 6, lane = tid & 63;
    if (tid == 0) s_carry = 0;
    __syncthreads();
    for (int base = 0; base < N; base += 1024) {
        const int i = base + tid;
        const int v = (i < N) ? cnt[i] : 0;
        int x = v;                                  // inclusive intra-wave scan
#pragma unroll
        for (int d = 1; d < 64; d <<= 1) {
            const int y = __shfl_up(x, d, 64);
            if (lane >= d) x += y;
        }
        if (lane == 63) wsum[wave] = x;
        __syncthreads();
        if (wave == 0 && lane < 16) {
            int w = wsum[lane];
#pragma unroll
            for (int d = 1; d < 16; d <<= 1) {
                const int y = __shfl_up(w, d, 64);
                if (lane >= d) w += y;              // lanes 16..63 inactive
            }
            wsum[lane] = w;                         // inclusive wave-prefix
        }
        __syncthreads();
        const int woff = (wave == 0) ? 0 : wsum[wave - 1];
        const int carry = s_carry;
        if (i < N) {
            const int s = carry + woff + x - v;     // exclusive
            start[i] = s;
            cursor[i] = s;
        }
        __syncthreads();
        if (tid == 0) s_carry = carry + wsum[15];
        __syncthreads();
    }
    if (tid == 0) start[N] = s_carry;
}

// ===================== edge_k: K-side TP + dot + softmax terms =====================
// LDS: 4 groups x 321 uint4 = 20544 B (group stride 5136 B; %128==16 ->
// the 4 concurrent group reads land on disjoint bank quads, conflict-free).
// Per-group chunk map (uint4 idx): [0,128)=w1(k*32+j), [128,192)=w3(k2*32+j),
// [192,256)=w2(k*32+j), [256,320)=w4|w5 interleaved (k*32+j).
__global__ __launch_bounds__(BS, 3) void edge_k(
    const float* __restrict__ node_ft,
    const int*   __restrict__ ei,
    const float* __restrict__ edge_sh,
    const float* __restrict__ edge_scalars,
    const float* __restrict__ fck_w1,
    const float* __restrict__ fck_w2,
    const float* __restrict__ qd,
    int*   __restrict__ cursor,
    float* __restrict__ exbuf,              // [E] CSR order
    float* __restrict__ sabuf,              // [E] edge order
    int*   __restrict__ posbuf,             // [E] edge order
    const int* __restrict__ flag,
    int N, int E)
{
    __shared__ uint4 sk4[4 * 321];          // 20544 B

    const int tid = threadIdx.x;
    // ---- stage weights (bf16, group-split, permuted) ----
    for (int idx = tid; idx < 4 * 320; idx += BS) {
        const int p = idx / 320;
        const int local = idx - p * 320;
        unsigned u0, u1, u2, u3;
        if (local < 256) {
            int j, c0;
            if (local < 128) {                       // w1: i = 4p+k, 8 cols
                const int k = local >> 5; j = local & 31; c0 = (4*p + k) * 8;
            } else if (local < 192) {                // w3: i0 = 4p+2k2, 2 i's x4
                const int l = local - 128; const int k2 = l >> 5; j = l & 31;
                c0 = 192 + (4*p + 2*k2) * 4;
            } else {                                 // w2: i = 2p+k, 8 cols
                const int l = local - 192; const int k = l >> 5; j = l & 31;
                c0 = 128 + (2*p + k) * 8;
            }
            const float* src = fck_w2 + j * 320 + c0;
            u0 = pk2(src[0], src[1]); u1 = pk2(src[2], src[3]);
            u2 = pk2(src[4], src[5]); u3 = pk2(src[6], src[7]);
        } else {                                     // w4|w5: i = 2p+k
            const int l = local - 256; const int k = l >> 5; const int j = l & 31;
            const int i = 2*p + k;
            const float* s4 = fck_w2 + j * 320 + 256 + i * 4;
            const float* s5 = fck_w2 + j * 320 + 288 + i * 4;
            u0 = pk2(s4[0], s4[1]); u1 = pk2(s4[2], s4[3]);
            u2 = pk2(s5[0], s5[1]); u3 = pk2(s5[2], s5[3]);
        }
        sk4[p * 321 + local] = make_uint4(u0, u1, u2, u3);
    }

    const int lane = tid & 63;
    const int p = lane >> 4;
    const int q = lane & 15;
    const int w = tid >> 6;
    const int e = blockIdx.x * EPB + w * 16 + q;
    const bool val = (e < E);
    const int ec = val ? e : (E - 1);

    const int is64 = *flag;
    const int snd = is64 ? ei[2*ec]       : ei[ec];
    const int rcv = is64 ? ei[2*(E + ec)] : ei[E + ec];

    int pos = 0;
    if (p == 0 && val) pos = atomicAdd(cursor + rcv, 1);  // one claimant/edge

    const float4 s4 = *(const float4*)(edge_sh + (size_t)ec * 4);
    const float sh_s = s4.x;
    const float sh_v[3] = {s4.y, s4.z, s4.w};

    const float* nf = node_ft + (size_t)snd * 40;

    __syncthreads();                                 // weights staged; no barriers below

    // ---- hidden activations (per lane; redundant across p) ----
    float hk[32];
    {
        float es[16];
        const float4* a0 = (const float4*)(edge_scalars + (size_t)ec * 16);
#pragma unroll
        for (int t = 0; t < 4; ++t) {
            const float4 v = a0[t];
            es[4*t+0]=v.x; es[4*t+1]=v.y; es[4*t+2]=v.z; es[4*t+3]=v.w;
        }
#pragma unroll
        for (int j = 0; j < 32; ++j) {
            float a = 0.f;
#pragma unroll
            for (int t = 0; t < 16; ++t) a += es[t] * fck_w1[t*32 + j];
            hk[j] = silu_f(a * 0.25f);
        }
    }

    const uint4* g = sk4 + p * 321;

    // ---- tk1 (xs -> scalar, this group's i = 4p+k) ----
    float K1[8] = {};
#pragma unroll 1
    for (int k = 0; k < 4; ++k) {
        const float x = nf[4*p + k];
        const uint4* gk = g + k * 32;
#pragma unroll
        for (int j = 0; j < 32; ++j) {
            const uint4 a = gk[j];
            const float t = x * hk[j];
            float wv[8]; up8(a, wv);
#pragma unroll
            for (int o = 0; o < 8; ++o) K1[o] += t*wv[o];
        }
    }

    // ---- tk3 (xs -> vec path scalar part; i0 = 4p+2k2, pairs) ----
    float K3[4] = {};
#pragma unroll 1
    for (int k2 = 0; k2 < 2; ++k2) {
        const int i0 = 4*p + 2*k2;
        const float xa = nf[i0], xb = nf[i0+1];
        const uint4* gk = g + 128 + k2 * 32;
#pragma unroll
        for (int j = 0; j < 32; ++j) {
            const uint4 a = gk[j];
            float wv[8]; up8(a, wv);
            const float ta = xa*hk[j], tb = xb*hk[j];
#pragma unroll
            for (int o = 0; o < 4; ++o) K3[o] += ta*wv[o] + tb*wv[4+o];
        }
    }

    // ---- tk2 + tk4/tk5 (vector inputs; this group's i = 2p+k) ----
    float K2[8] = {};
    float KV[12] = {};
    const float c3 = 0.57735026918962576f;
    const float c7 = 0.70710678118654752f;
#pragma unroll 1
    for (int k = 0; k < 2; ++k) {
        const int i = 2*p + k;
        const float x0 = nf[16 + 3*i], x1 = nf[17 + 3*i], x2 = nf[18 + 3*i];
        const float pv = (x0*sh_v[0] + x1*sh_v[1] + x2*sh_v[2]) * c3;
        float W4[4] = {}, W5[4] = {};
        const uint4* g2  = g + 192 + k * 32;
        const uint4* g45 = g + 256 + k * 32;
#pragma unroll
        for (int j = 0; j < 32; ++j) {
            const uint4 a = g2[j];
            const uint4 b = g45[j];
            const float t = pv * hk[j];
            float wv[8]; up8(a, wv);
#pragma unroll
            for (int o = 0; o < 8; ++o) K2[o] += t*wv[o];
            float wu[8]; up8(b, wu);
            const float h = hk[j];
#pragma unroll
            for (int o = 0; o < 4; ++o) {
                W4[o] += h*wu[o];
                W5[o] += h*wu[4+o];
            }
        }
        const float s0 = sh_s*x0, s1 = sh_s*x1, s2 = sh_s*x2;
        const float cx0 = c7*(x1*sh_v[2] - x2*sh_v[1]);
        const float cx1 = c7*(x2*sh_v[0] - x0*sh_v[2]);
        const float cx2 = c7*(x0*sh_v[1] - x1*sh_v[0]);
#pragma unroll
        for (int o = 0; o < 4; ++o) {
            KV[o*3+0] += s0*W4[o] + cx0*W5[o];
            KV[o*3+1] += s1*W4[o] + cx1*W5[o];
            KV[o*3+2] += s2*W4[o] + cx2*W5[o];
        }
    }

    // ---- combine partials across the 4 p-groups ----
#pragma unroll
    for (int o = 0; o < 8; ++o) K1[o] = wred4(K1[o]);
#pragma unroll
    for (int o = 0; o < 8; ++o) K2[o] = wred4(K2[o]);
#pragma unroll
    for (int o = 0; o < 4; ++o) K3[o] = wred4(K3[o]);
#pragma unroll
    for (int o = 0; o < 12; ++o) KV[o] = wred4(KV[o]);

    if (p == 0 && val) {
        float qdr[20];
        {
            const float4* rp = (const float4*)(qd + (size_t)rcv * 20);
#pragma unroll
            for (int t = 0; t < 5; ++t) {
                const float4 a = rp[t];
                qdr[4*t+0]=a.x; qdr[4*t+1]=a.y; qdr[4*t+2]=a.z; qdr[4*t+3]=a.w;
            }
        }
        float ds = 0.f;
#pragma unroll
        for (int o = 0; o < 8; ++o) ds += qdr[o] * (sh_s*K1[o] + K2[o]);
        float dv = 0.f;
#pragma unroll
        for (int o = 0; o < 4; ++o)
#pragma unroll
            for (int c = 0; c < 3; ++c)
                dv += qdr[8 + o*3 + c] * (K3[o]*sh_v[c] + KV[o*3+c]);
        const float dot = ds * 4.0343567508008e-3f + dv * 2.0171788261497e-3f;
        const float sa = __expf(0.5f * dot);
        exbuf[pos] = sa*sa; sabuf[e] = sa; posbuf[e] = pos;
    }
}

// ===================== edge_v_a: V scalar outputs (cols [0,384)) =====================
// LDS: 4 x 385 uint4 = 24640 B (stride 6160 B, %128==16 -> conflict-free).
// Chunk map: [0,256)=w1 ((k*32+j)*2+h), [256,384)=w2 (256+(k*32+j)*2+h).
// shs folded into xs (f32, in registers) -> only W is bf16-rounded.
__global__ __launch_bounds__(BS, 3) void edge_v_a(
    const float* __restrict__ node_ft,
    const int*   __restrict__ ei,
    const float* __restrict__ edge_sh,
    const float* __restrict__ edge_scalars,
    const float* __restrict__ fcv_w1,
    const float* __restrict__ fcv_w2,
    const float* __restrict__ sabuf,
    const int*   __restrict__ posbuf,
    float* __restrict__ vbuf,               // [E,40]
    const int* __restrict__ flag,
    int E)
{
    __shared__ uint4 sa4[4 * 385];          // 24640 B

    const int tid = threadIdx.x;
    for (int idx = tid; idx < 4 * 384; idx += BS) {
        const int p = idx / 384;
        const int local = idx - p * 384;
        int j, c0;
        if (local < 256) {                           // w1: i = 4p+k, 16 cols in 2 halves
            const int k = local >> 6; j = (local >> 1) & 31; const int h = local & 1;
            c0 = (4*p + k) * 16 + 8*h;
        } else {                                     // w2: i = 2p+k
            const int l = local - 256;
            const int k = l >> 6; j = (l >> 1) & 31; const int h = l & 1;
            c0 = 256 + (2*p + k) * 16 + 8*h;
        }
        const float* src = fcv_w2 + j * 640 + c0;
        sa4[p * 385 + local] = make_uint4(
            pk2(src[0], src[1]), pk2(src[2], src[3]),
            pk2(src[4], src[5]), pk2(src[6], src[7]));
    }

    const int lane = tid & 63;
    const int p = lane >> 4;
    const int q = lane & 15;
    const int w = tid >> 6;
    const int e = blockIdx.x * EPB + w * 16 + q;
    const bool val = (e < E);
    const int ec = val ? e : (E - 1);

    const int is64 = *flag;
    const int snd = is64 ? ei[2*ec] : ei[ec];

    const float4 s4 = *(const float4*)(edge_sh + (size_t)ec * 4);
    const float sh_s = s4.x;

    const float* nf = node_ft + (size_t)snd * 40;

    __syncthreads();

    float hv[32];
    {
        float es[16];
        const float4* a0 = (const float4*)(edge_scalars + (size_t)ec * 16);
#pragma unroll
        for (int t = 0; t < 4; ++t) {
            const float4 v = a0[t];
            es[4*t+0]=v.x; es[4*t+1]=v.y; es[4*t+2]=v.z; es[4*t+3]=v.w;
        }
#pragma unroll
        for (int j = 0; j < 32; ++j) {
            float a = 0.f;
#pragma unroll
            for (int t = 0; t < 16; ++t) a += es[t] * fcv_w1[t*32 + j];
            hv[j] = silu_f(a * 0.25f);
        }
    }

    const uint4* g = sa4 + p * 385;
    float A[16] = {};

    // ---- v1 path (xs*shs, i = 4p+k) ----
#pragma unroll 1
    for (int k = 0; k < 4; ++k) {
        const float x = nf[4*p + k] * sh_s;
        const uint4* gk = g + k * 64;
#pragma unroll
        for (int j = 0; j < 32; ++j) {
            const uint4 a = gk[2*j];
            const uint4 b = gk[2*j + 1];
            const float t = x * hv[j];
            float wv[16]; up8(a, wv); up8(b, wv + 8);
#pragma unroll
            for (int o = 0; o < 16; ++o) A[o] += t*wv[o];
        }
    }

    // ---- v2 path (xv.shv, i = 2p+k), accumulate into the same outputs ----
    const float c3 = 0.57735026918962576f;
#pragma unroll 1
    for (int k = 0; k < 2; ++k) {
        const int i = 2*p + k;
        const float pv = (nf[16+3*i]*s4.y + nf[17+3*i]*s4.z + nf[18+3*i]*s4.w) * c3;
        const uint4* gk = g + 256 + k * 64;
#pragma unroll
        for (int j = 0; j < 32; ++j) {
            const uint4 a = gk[2*j];
            const uint4 b = gk[2*j + 1];
            const float t = pv * hv[j];
            float wv[16]; up8(a, wv); up8(b, wv + 8);
#pragma unroll
            for (int o = 0; o < 16; ++o) A[o] += t*wv[o];
        }
    }

#pragma unroll
    for (int o = 0; o < 16; ++o) A[o] = wred4(A[o]);

    if (p == 0 && val) {
        const float cs = 0.03608439182435161f;   // (1/sqrt32)*(1/sqrt24)
        const float sa = sabuf[e];
        const int pos = posbuf[e];
        float4* vp = (float4*)(vbuf + (size_t)pos * 40);
#pragma unroll
        for (int t = 0; t < 4; ++t) {
            float4 r;
            r.x = sa * A[4*t+0] * cs; r.y = sa * A[4*t+1] * cs;
            r.z = sa * A[4*t+2] * cs; r.w = sa * A[4*t+3] * cs;
            vp[t] = r;
        }
    }
}

// ===================== edge_v_b: V vector outputs (cols [384,640)) =====================
// LDS: 4 x 257 uint4 = 16448 B (stride 4112 B, %128==16 -> conflict-free).
// Chunk map: [0,128)=w3 (k*32+j), [128,192)=w4 (k*32+j), [192,256)=w5 (k*32+j).
__global__ __launch_bounds__(BS, 3) void edge_v_b(
    const float* __restrict__ node_ft,
    const int*   __restrict__ ei,
    const float* __restrict__ edge_sh,
    const float* __restrict__ edge_scalars,
    const float* __restrict__ fcv_w1,
    const float* __restrict__ fcv_w2,
    const float* __restrict__ sabuf,
    const int*   __restrict__ posbuf,
    float* __restrict__ vbuf,               // [E,40]
    const int* __restrict__ flag,
    int E)
{
    __shared__ uint4 sb4[4 * 257];          // 16448 B

    const int tid = threadIdx.x;
    for (int idx = tid; idx < 4 * 256; idx += BS) {
        const int p = idx >> 8;
        const int local = idx & 255;
        int j, c0;
        if (local < 128) {                           // w3: i = 4p+k
            const int k = local >> 5; j = local & 31; c0 = 384 + (4*p + k) * 8;
        } else if (local < 192) {                    // w4: i = 2p+k
            const int l = local - 128; const int k = l >> 5; j = l & 31;
            c0 = 512 + (2*p + k) * 8;
        } else {                                     // w5: i = 2p+k
            const int l = local - 192; const int k = l >> 5; j = l & 31;
            c0 = 576 + (2*p + k) * 8;
        }
        const float* src = fcv_w2 + j * 640 + c0;
        sb4[p * 257 + local] = make_uint4(
            pk2(src[0], src[1]), pk2(src[2], src[3]),
            pk2(src[4], src[5]), pk2(src[6], src[7]));
    }

    const int lane = tid & 63;
    const int p = lane >> 4;
    const int q = lane & 15;
    const int w = tid >> 6;
    const int e = blockIdx.x * EPB + w * 16 + q;
    const bool val = (e < E);
    const int ec = val ? e : (E - 1);

    const int is64 = *flag;
    const int snd = is64 ? ei[2*ec] : ei[ec];

    const float4 s4 = *(const float4*)(edge_sh + (size_t)ec * 4);
    const float sh_s = s4.x;
    const float sh_v[3] = {s4.y, s4.z, s4.w};

    const float* nf = node_ft + (size_t)snd * 40;

    __syncthreads();

    float hv[32];
    {
        float es[16];
        const float4* a0 = (const float4*)(edge_scalars + (size_t)ec * 16);
#pragma unroll
        for (int t = 0; t < 4; ++t) {
            const float4 v = a0[t];
            es[4*t+0]=v.x; es[4*t+1]=v.y; es[4*t+2]=v.z; es[4*t+3]=v.w;
        }
#pragma unroll
        for (int j = 0; j < 32; ++j) {
            float a = 0.f;
#pragma unroll
            for (int t = 0; t < 16; ++t) a += es[t] * fcv_w1[t*32 + j];
            hv[j] = silu_f(a * 0.25f);
        }
    }

    const uint4* g = sb4 + p * 257;

    // ---- v3 path (xs (x) shv; shv applied after reduction) ----
    float T3[8] = {};
#pragma unroll 1
    for (int k = 0; k < 4; ++k) {
        const float x = nf[4*p + k];
        const uint4* gk = g + k * 32;
#pragma unroll
        for (int j = 0; j < 32; ++j) {
            const uint4 a = gk[j];
            const float t = x * hv[j];
            float wv[8]; up8(a, wv);
#pragma unroll
            for (int o = 0; o < 8; ++o) T3[o] += t*wv[o];
        }
    }

    // ---- v4/v5 paths (i = 2p+k); shs & cross folded per-k ----
    float R[24] = {};
    const float c7 = 0.70710678118654752f;
#pragma unroll 1
    for (int k = 0; k < 2; ++k) {
        const int i = 2*p + k;
        const float x0 = nf[16 + 3*i], x1 = nf[17 + 3*i], x2 = nf[18 + 3*i];
        float W4[8] = {}, W5[8] = {};
        const uint4* g4 = g + 128 + k * 32;
        const uint4* g5 = g + 192 + k * 32;
#pragma unroll
        for (int j = 0; j < 32; ++j) {
            const uint4 a = g4[j];
            const uint4 b = g5[j];
            const float h = hv[j];
            float wv[8], wu[8]; up8(a, wv); up8(b, wu);
#pragma unroll
            for (int o = 0; o < 8; ++o) {
                W4[o] += h*wv[o];
                W5[o] += h*wu[o];
            }
        }
        const float s0 = sh_s*x0, s1 = sh_s*x1, s2 = sh_s*x2;
        const float cx0 = c7*(x1*sh_v[2] - x2*sh_v[1]);
        const float cx1 = c7*(x2*sh_v[0] - x0*sh_v[2]);
        const float cx2 = c7*(x0*sh_v[1] - x1*sh_v[0]);
#pragma unroll
        for (int o = 0; o < 8; ++o) {
            R[o*3+0] += s0*W4[o] + cx0*W5[o];
            R[o*3+1] += s1*W4[o] + cx1*W5[o];
            R[o*3+2] += s2*W4[o] + cx2*W5[o];
        }
    }

#pragma unroll
    for (int o = 0; o < 8; ++o) T3[o] = wred4(T3[o]);
#pragma unroll
    for (int o = 0; o < 24; ++o) R[o] = wred4(R[o]);

    if (p == 0 && val) {
        const float sc = 0.03125f;               // (1/sqrt32)*(1/sqrt32)
        const float sa = sabuf[e];
        const int pos = posbuf[e];
        float row[24];
#pragma unroll
        for (int o = 0; o < 8; ++o)
#pragma unroll
            for (int c = 0; c < 3; ++c)
                row[o*3+c] = sa * (T3[o]*sh_v[c] + R[o*3+c]) * sc;
        float4* vp = (float4*)(vbuf + (size_t)pos * 40 + 16);
#pragma unroll
        for (int t = 0; t < 6; ++t) {
            float4 r; r.x = row[4*t+0]; r.y = row[4*t+1]; r.z = row[4*t+2]; r.w = row[4*t+3];
            vp[t] = r;
        }
    }
}

__global__ __launch_bounds__(256) void node_reduce(
    const int*   __restrict__ start,
    const float* __restrict__ exbuf,
    const float* __restrict__ vbuf,
    float* __restrict__ out, int N)
{
    const int wave = threadIdx.x >> 6;
    const int lane = threadIdx.x & 63;
    const int n = blockIdx.x * 4 + wave;
    if (n >= N) return;
    const int r0 = start[n], r1 = start[n + 1];
    float z = 0.f, comp = 0.f;
    for (int r = r0; r < r1; ++r) {
        z += exbuf[r];
        if (lane < 40) comp += vbuf[(size_t)r * 40 + lane];
    }
    if (lane < 40)
        out[(size_t)n * 40 + lane] = (z > 0.f) ? comp * rsqrtf(z) : 0.f;
}

extern "C" void kernel_launch(void* const* d_in, const int* in_sizes, int n_in,
                              void* d_out, int out_size, void* d_ws, size_t ws_size,
                              hipStream_t stream) {
    const float* node_ft      = (const float*)d_in[0];
    const int*   edge_index   = (const int*)  d_in[1];
    const float* edge_sh      = (const float*)d_in[2];
    const float* edge_scalars = (const float*)d_in[3];
    const float* w_q_s        = (const float*)d_in[4];
    const float* w_q_v        = (const float*)d_in[5];
    const float* fck_w1       = (const float*)d_in[6];
    const float* fck_w2       = (const float*)d_in[7];
    const float* fcv_w1       = (const float*)d_in[8];
    const float* fcv_w2       = (const float*)d_in[9];
    const float* wdot_s       = (const float*)d_in[10];
    const float* wdot_v       = (const float*)d_in[11];

    const int N = in_sizes[0] / 40;
    const int E = in_sizes[2] / 4;

    float* ws    = (float*)d_ws;
    float* qd    = ws;                               // N*20
    int*   cnt   = (int*)(ws + (size_t)N * 20);      // N
    int*   start = cnt + N;                          // N+1
    int*   curs  = start + N + 1;                    // N
    int*   flg   = curs + N;                         // 1
    size_t off   = (size_t)N * 20 + N + (N + 1) + N + 1;
    off = (off + 3) & ~(size_t)3;                    // 16B align
    float* exbuf  = ws + off;                        // E
    float* sabuf  = exbuf + E;                       // E
    int*   posbuf = (int*)(sabuf + E);               // E
    float* vbuf   = (float*)(posbuf + E);            // E*40 (E%4==0 -> aligned)

    float* out = (float*)d_out;

    const int EB = (E + EPB - 1) / EPB;

    hipLaunchKernelGGL(node_pre, dim3((N + 255) / 256), dim3(256), 0, stream,
                       node_ft, edge_index, w_q_s, w_q_v, wdot_s, wdot_v,
                       qd, cnt, flg, N, E);
    hipLaunchKernelGGL(count_edges, dim3((E + 255) / 256), dim3(256), 0, stream,
                       edge_index, cnt, flg, E);
    hipLaunchKernelGGL(scan_kernel, dim3(1), dim3(1024), 0, stream,
                       cnt, start, curs, N);
    hipLaunchKernelGGL(edge_k, dim3(EB), dim3(BS), 0, stream,
                       node_ft, edge_index, edge_sh, edge_scalars,
                       fck_w1, fck_w2, qd, curs, exbuf, sabuf, posbuf, flg, N, E);
    hipLaunchKernelGGL(edge_v_a, dim3(EB), dim3(BS), 0, stream,
                       node_ft, edge_index, edge_sh, edge_scalars,
                       fcv_w1, fcv_w2, sabuf, posbuf, vbuf, flg, E);
    hipLaunchKernelGGL(edge_v_b, dim3(EB), dim3(BS), 0, stream,
                       node_ft, edge_index, edge_sh, edge_scalars,
                       fcv_w1, fcv_w2, sabuf, posbuf, vbuf, flg, E);
    hipLaunchKernelGGL(node_reduce, dim3((N + 3) / 4), dim3(256), 0, stream,
                       start, exbuf, vbuf, out, N);
}

// Round 4
// 370.418 us; speedup vs baseline: 2.7324x; 2.7324x over previous
//
#include <hip/hip_runtime.h>

// GraphAttention (e3nn-style) on MI355X — Round 8: i-split, 1 edge/thread,
// no launch-bounds cap, unroll-8 inner loops.
// Round-7 post-mortem: __launch_bounds__(256,3) made the compiler allocate 84
// VGPRs for ~150 live values -> 2 GB/dispatch scratch traffic (FETCH 774MB /
// WRITE 1.24GB on edge_v_a), 498us. The i-split itself is verified good
// (0 bank conflicts, correct, occupancy 30%). Fix: (a) remove the min-waves
// cap entirely; (b) #pragma unroll 8 on the j-loops so <=8 uint4 ds_reads in
// flight instead of 32 (the unroll pipeline was the VGPR pressure source).
//
// Dims: M0=16 M1=8 Q0=8 Q1=4 O0=16 O1=8 EDGE_BASIS=16 HIDDEN=32
// TPK [32][320]: w1[0,128) w2[128,192) w3[192,256) w4[256,288) w5[288,320)
// TPV [32][640]: w1[0,256) w2[256,384) w3[384,512) w4[512,576) w5[576,640)
//
// Pipeline: node_pre | count_edges | scan | edge_k | edge_v_a | edge_v_b | node_reduce
// ws (4B units): qd[N*20] | cnt[N] | start[N+1] | cursor[N] | flag | pad |
//                exbuf[E] | sabuf[E] | posbuf[E] | vbuf[E*40]

#define BS 256           // threads per block (edge kernels)
#define EPB 64           // edges per block: 4 waves x 16 q-lanes x 1 edge

__device__ __forceinline__ float silu_f(float x) {
    return x * (1.0f / (1.0f + __expf(-x)));
}
__device__ __forceinline__ unsigned short f2b(float f) {   // f32 -> bf16 (RNE)
    unsigned u = __float_as_uint(f);
    u += 0x7fffu + ((u >> 16) & 1u);
    return (unsigned short)(u >> 16);
}
__device__ __forceinline__ float bl(unsigned u) {          // low bf16 -> f32
    return __uint_as_float(u << 16);
}
__device__ __forceinline__ float bh(unsigned u) {          // high bf16 -> f32
    return __uint_as_float(u & 0xffff0000u);
}
__device__ __forceinline__ unsigned pk2(float a, float b) { // pack 2 bf16
    return (unsigned)f2b(a) | ((unsigned)f2b(b) << 16);
}
__device__ __forceinline__ void up8(const uint4 a, float* w) {
    w[0] = bl(a.x); w[1] = bh(a.x); w[2] = bl(a.y); w[3] = bh(a.y);
    w[4] = bl(a.z); w[5] = bh(a.z); w[6] = bl(a.w); w[7] = bh(a.w);
}
__device__ __forceinline__ float wred4(float v) {          // sum over 4 p-groups
    v += __shfl_xor(v, 16);
    v += __shfl_xor(v, 32);
    return v;
}

__global__ __launch_bounds__(256) void node_pre(
    const float* __restrict__ node_ft,
    const int*   __restrict__ ei,
    const float* __restrict__ w_q_s, const float* __restrict__ w_q_v,
    const float* __restrict__ wdot_s, const float* __restrict__ wdot_v,
    float* __restrict__ qd, int* __restrict__ cnt, int* __restrict__ flag,
    int N, int E)
{
    const int n = blockIdx.x * blockDim.x + threadIdx.x;
    if (n == 0) {
        int acc = 0;
        const int kmax = (E < 64) ? E : 64;
        for (int k = 0; k < kmax; ++k) acc |= ei[2*k + 1];
        *flag = (acc == 0) ? 1 : 0;   // int64 layout => odd words all zero
    }
    if (n >= N) return;
    cnt[n] = 0;

    const float* nf = node_ft + (size_t)n * 40;
    float xs[16];
#pragma unroll
    for (int i = 0; i < 16; ++i) xs[i] = nf[i];
    float q[8];
#pragma unroll
    for (int o = 0; o < 8; ++o) {
        float a = 0.f;
#pragma unroll
        for (int i = 0; i < 16; ++i) a += xs[i] * w_q_s[i*8 + o];
        q[o] = a * 0.25f;
    }
    float* qdn = qd + (size_t)n * 20;
#pragma unroll
    for (int j = 0; j < 8; ++j) {
        float a = 0.f;
#pragma unroll
        for (int i = 0; i < 8; ++i) a += q[i] * wdot_s[i*8 + j];
        qdn[j] = a;
    }
    float xv[8][3];
#pragma unroll
    for (int i = 0; i < 8; ++i)
#pragma unroll
        for (int c = 0; c < 3; ++c) xv[i][c] = nf[16 + i*3 + c];
    float qv[4][3];
#pragma unroll
    for (int o = 0; o < 4; ++o)
#pragma unroll
        for (int c = 0; c < 3; ++c) {
            float a = 0.f;
#pragma unroll
            for (int i = 0; i < 8; ++i) a += xv[i][c] * w_q_v[i*4 + o];
            qv[o][c] = a * 0.35355339059327379f;
        }
#pragma unroll
    for (int j = 0; j < 4; ++j)
#pragma unroll
        for (int c = 0; c < 3; ++c) {
            float a = 0.f;
#pragma unroll
            for (int i = 0; i < 4; ++i) a += qv[i][c] * wdot_v[i*4 + j];
            qdn[8 + j*3 + c] = a;
        }
}

__global__ __launch_bounds__(256) void count_edges(
    const int* __restrict__ ei, int* __restrict__ cnt,
    const int* __restrict__ flag, int E)
{
    const int e = blockIdx.x * blockDim.x + threadIdx.x;
    if (e >= E) return;
    const int is64 = *flag;
    const int rcv = is64 ? ei[2*(E + e)] : ei[E + e];
    atomicAdd(cnt + rcv, 1);
}

// 1 block, 1024 threads; shuffle-based scan (few barriers).
__global__ __launch_bounds__(1024) void scan_kernel(
    const int* __restrict__ cnt, int* __restrict__ start,
    int* __restrict__ cursor, int N)
{
    __shared__ int wsum[16];
    __shared__ int s_carry;
    const int tid = threadIdx.x, wave = tid >> 6, lane = tid & 63;
    if (tid == 0) s_carry = 0;
    __syncthreads();
    for (int base = 0; base < N; base += 1024) {
        const int i = base + tid;
        const int v = (i < N) ? cnt[i] : 0;
        int x = v;                                  // inclusive intra-wave scan
#pragma unroll
        for (int d = 1; d < 64; d <<= 1) {
            const int y = __shfl_up(x, d, 64);
            if (lane >= d) x += y;
        }
        if (lane == 63) wsum[wave] = x;
        __syncthreads();
        if (wave == 0 && lane < 16) {
            int w = wsum[lane];
#pragma unroll
            for (int d = 1; d < 16; d <<= 1) {
                const int y = __shfl_up(w, d, 64);
                if (lane >= d) w += y;              // lanes 16..63 inactive
            }
            wsum[lane] = w;                         // inclusive wave-prefix
        }
        __syncthreads();
        const int woff = (wave == 0) ? 0 : wsum[wave - 1];
        const int carry = s_carry;
        if (i < N) {
            const int s = carry + woff + x - v;     // exclusive
            start[i] = s;
            cursor[i] = s;
        }
        __syncthreads();
        if (tid == 0) s_carry = carry + wsum[15];
        __syncthreads();
    }
    if (tid == 0) start[N] = s_carry;
}

// ===================== edge_k: K-side TP + dot + softmax terms =====================
// LDS: 4 groups x 321 uint4 = 20544 B (group stride 5136 B; %128==16 ->
// the 4 concurrent group reads land on disjoint bank quads, conflict-free).
// Per-group chunk map (uint4 idx): [0,128)=w1(k*32+j), [128,192)=w3(k2*32+j),
// [192,256)=w2(k*32+j), [256,320)=w4|w5 interleaved (k*32+j).
__global__ __launch_bounds__(BS) void edge_k(
    const float* __restrict__ node_ft,
    const int*   __restrict__ ei,
    const float* __restrict__ edge_sh,
    const float* __restrict__ edge_scalars,
    const float* __restrict__ fck_w1,
    const float* __restrict__ fck_w2,
    const float* __restrict__ qd,
    int*   __restrict__ cursor,
    float* __restrict__ exbuf,              // [E] CSR order
    float* __restrict__ sabuf,              // [E] edge order
    int*   __restrict__ posbuf,             // [E] edge order
    const int* __restrict__ flag,
    int N, int E)
{
    __shared__ uint4 sk4[4 * 321];          // 20544 B

    const int tid = threadIdx.x;
    // ---- stage weights (bf16, group-split, permuted) ----
    for (int idx = tid; idx < 4 * 320; idx += BS) {
        const int p = idx / 320;
        const int local = idx - p * 320;
        unsigned u0, u1, u2, u3;
        if (local < 256) {
            int j, c0;
            if (local < 128) {                       // w1: i = 4p+k, 8 cols
                const int k = local >> 5; j = local & 31; c0 = (4*p + k) * 8;
            } else if (local < 192) {                // w3: i0 = 4p+2k2, 2 i's x4
                const int l = local - 128; const int k2 = l >> 5; j = l & 31;
                c0 = 192 + (4*p + 2*k2) * 4;
            } else {                                 // w2: i = 2p+k, 8 cols
                const int l = local - 192; const int k = l >> 5; j = l & 31;
                c0 = 128 + (2*p + k) * 8;
            }
            const float* src = fck_w2 + j * 320 + c0;
            u0 = pk2(src[0], src[1]); u1 = pk2(src[2], src[3]);
            u2 = pk2(src[4], src[5]); u3 = pk2(src[6], src[7]);
        } else {                                     // w4|w5: i = 2p+k
            const int l = local - 256; const int k = l >> 5; const int j = l & 31;
            const int i = 2*p + k;
            const float* s4 = fck_w2 + j * 320 + 256 + i * 4;
            const float* s5 = fck_w2 + j * 320 + 288 + i * 4;
            u0 = pk2(s4[0], s4[1]); u1 = pk2(s4[2], s4[3]);
            u2 = pk2(s5[0], s5[1]); u3 = pk2(s5[2], s5[3]);
        }
        sk4[p * 321 + local] = make_uint4(u0, u1, u2, u3);
    }

    const int lane = tid & 63;
    const int p = lane >> 4;
    const int q = lane & 15;
    const int w = tid >> 6;
    const int e = blockIdx.x * EPB + w * 16 + q;
    const bool val = (e < E);
    const int ec = val ? e : (E - 1);

    const int is64 = *flag;
    const int snd = is64 ? ei[2*ec]       : ei[ec];
    const int rcv = is64 ? ei[2*(E + ec)] : ei[E + ec];

    int pos = 0;
    if (p == 0 && val) pos = atomicAdd(cursor + rcv, 1);  // one claimant/edge

    const float4 s4 = *(const float4*)(edge_sh + (size_t)ec * 4);
    const float sh_s = s4.x;
    const float sh_v[3] = {s4.y, s4.z, s4.w};

    const float* nf = node_ft + (size_t)snd * 40;

    __syncthreads();                                 // weights staged; no barriers below

    // ---- hidden activations (per lane; redundant across p) ----
    float hk[32];
    {
        float es[16];
        const float4* a0 = (const float4*)(edge_scalars + (size_t)ec * 16);
#pragma unroll
        for (int t = 0; t < 4; ++t) {
            const float4 v = a0[t];
            es[4*t+0]=v.x; es[4*t+1]=v.y; es[4*t+2]=v.z; es[4*t+3]=v.w;
        }
#pragma unroll 8
        for (int j = 0; j < 32; ++j) {
            float a = 0.f;
#pragma unroll
            for (int t = 0; t < 16; ++t) a += es[t] * fck_w1[t*32 + j];
            hk[j] = silu_f(a * 0.25f);
        }
    }

    const uint4* g = sk4 + p * 321;

    // ---- tk1 (xs -> scalar, this group's i = 4p+k) ----
    float K1[8] = {};
#pragma unroll 1
    for (int k = 0; k < 4; ++k) {
        const float x = nf[4*p + k];
        const uint4* gk = g + k * 32;
#pragma unroll 8
        for (int j = 0; j < 32; ++j) {
            const uint4 a = gk[j];
            const float t = x * hk[j];
            float wv[8]; up8(a, wv);
#pragma unroll
            for (int o = 0; o < 8; ++o) K1[o] += t*wv[o];
        }
    }

    // ---- tk3 (xs -> vec path scalar part; i0 = 4p+2k2, pairs) ----
    float K3[4] = {};
#pragma unroll 1
    for (int k2 = 0; k2 < 2; ++k2) {
        const int i0 = 4*p + 2*k2;
        const float xa = nf[i0], xb = nf[i0+1];
        const uint4* gk = g + 128 + k2 * 32;
#pragma unroll 8
        for (int j = 0; j < 32; ++j) {
            const uint4 a = gk[j];
            float wv[8]; up8(a, wv);
            const float ta = xa*hk[j], tb = xb*hk[j];
#pragma unroll
            for (int o = 0; o < 4; ++o) K3[o] += ta*wv[o] + tb*wv[4+o];
        }
    }

    // ---- tk2 + tk4/tk5 (vector inputs; this group's i = 2p+k) ----
    float K2[8] = {};
    float KV[12] = {};
    const float c3 = 0.57735026918962576f;
    const float c7 = 0.70710678118654752f;
#pragma unroll 1
    for (int k = 0; k < 2; ++k) {
        const int i = 2*p + k;
        const float x0 = nf[16 + 3*i], x1 = nf[17 + 3*i], x2 = nf[18 + 3*i];
        const float pv = (x0*sh_v[0] + x1*sh_v[1] + x2*sh_v[2]) * c3;
        float W4[4] = {}, W5[4] = {};
        const uint4* g2  = g + 192 + k * 32;
        const uint4* g45 = g + 256 + k * 32;
#pragma unroll 8
        for (int j = 0; j < 32; ++j) {
            const uint4 a = g2[j];
            const uint4 b = g45[j];
            const float t = pv * hk[j];
            float wv[8]; up8(a, wv);
#pragma unroll
            for (int o = 0; o < 8; ++o) K2[o] += t*wv[o];
            float wu[8]; up8(b, wu);
            const float h = hk[j];
#pragma unroll
            for (int o = 0; o < 4; ++o) {
                W4[o] += h*wu[o];
                W5[o] += h*wu[4+o];
            }
        }
        const float s0 = sh_s*x0, s1 = sh_s*x1, s2 = sh_s*x2;
        const float cx0 = c7*(x1*sh_v[2] - x2*sh_v[1]);
        const float cx1 = c7*(x2*sh_v[0] - x0*sh_v[2]);
        const float cx2 = c7*(x0*sh_v[1] - x1*sh_v[0]);
#pragma unroll
        for (int o = 0; o < 4; ++o) {
            KV[o*3+0] += s0*W4[o] + cx0*W5[o];
            KV[o*3+1] += s1*W4[o] + cx1*W5[o];
            KV[o*3+2] += s2*W4[o] + cx2*W5[o];
        }
    }

    // ---- combine partials across the 4 p-groups ----
#pragma unroll
    for (int o = 0; o < 8; ++o) K1[o] = wred4(K1[o]);
#pragma unroll
    for (int o = 0; o < 8; ++o) K2[o] = wred4(K2[o]);
#pragma unroll
    for (int o = 0; o < 4; ++o) K3[o] = wred4(K3[o]);
#pragma unroll
    for (int o = 0; o < 12; ++o) KV[o] = wred4(KV[o]);

    if (p == 0 && val) {
        float qdr[20];
        {
            const float4* rp = (const float4*)(qd + (size_t)rcv * 20);
#pragma unroll
            for (int t = 0; t < 5; ++t) {
                const float4 a = rp[t];
                qdr[4*t+0]=a.x; qdr[4*t+1]=a.y; qdr[4*t+2]=a.z; qdr[4*t+3]=a.w;
            }
        }
        float ds = 0.f;
#pragma unroll
        for (int o = 0; o < 8; ++o) ds += qdr[o] * (sh_s*K1[o] + K2[o]);
        float dv = 0.f;
#pragma unroll
        for (int o = 0; o < 4; ++o)
#pragma unroll
            for (int c = 0; c < 3; ++c)
                dv += qdr[8 + o*3 + c] * (K3[o]*sh_v[c] + KV[o*3+c]);
        const float dot = ds * 4.0343567508008e-3f + dv * 2.0171788261497e-3f;
        const float sa = __expf(0.5f * dot);
        exbuf[pos] = sa*sa; sabuf[e] = sa; posbuf[e] = pos;
    }
}

// ===================== edge_v_a: V scalar outputs (cols [0,384)) =====================
// LDS: 4 x 385 uint4 = 24640 B (stride 6160 B, %128==16 -> conflict-free).
// Chunk map: [0,256)=w1 ((k*32+j)*2+h), [256,384)=w2 (256+(k*32+j)*2+h).
// shs folded into xs (f32, in registers) -> only W is bf16-rounded.
__global__ __launch_bounds__(BS) void edge_v_a(
    const float* __restrict__ node_ft,
    const int*   __restrict__ ei,
    const float* __restrict__ edge_sh,
    const float* __restrict__ edge_scalars,
    const float* __restrict__ fcv_w1,
    const float* __restrict__ fcv_w2,
    const float* __restrict__ sabuf,
    const int*   __restrict__ posbuf,
    float* __restrict__ vbuf,               // [E,40]
    const int* __restrict__ flag,
    int E)
{
    __shared__ uint4 sa4[4 * 385];          // 24640 B

    const int tid = threadIdx.x;
    for (int idx = tid; idx < 4 * 384; idx += BS) {
        const int p = idx / 384;
        const int local = idx - p * 384;
        int j, c0;
        if (local < 256) {                           // w1: i = 4p+k, 16 cols in 2 halves
            const int k = local >> 6; j = (local >> 1) & 31; const int h = local & 1;
            c0 = (4*p + k) * 16 + 8*h;
        } else {                                     // w2: i = 2p+k
            const int l = local - 256;
            const int k = l >> 6; j = (l >> 1) & 31; const int h = l & 1;
            c0 = 256 + (2*p + k) * 16 + 8*h;
        }
        const float* src = fcv_w2 + j * 640 + c0;
        sa4[p * 385 + local] = make_uint4(
            pk2(src[0], src[1]), pk2(src[2], src[3]),
            pk2(src[4], src[5]), pk2(src[6], src[7]));
    }

    const int lane = tid & 63;
    const int p = lane >> 4;
    const int q = lane & 15;
    const int w = tid >> 6;
    const int e = blockIdx.x * EPB + w * 16 + q;
    const bool val = (e < E);
    const int ec = val ? e : (E - 1);

    const int is64 = *flag;
    const int snd = is64 ? ei[2*ec] : ei[ec];

    const float4 s4 = *(const float4*)(edge_sh + (size_t)ec * 4);
    const float sh_s = s4.x;

    const float* nf = node_ft + (size_t)snd * 40;

    __syncthreads();

    float hv[32];
    {
        float es[16];
        const float4* a0 = (const float4*)(edge_scalars + (size_t)ec * 16);
#pragma unroll
        for (int t = 0; t < 4; ++t) {
            const float4 v = a0[t];
            es[4*t+0]=v.x; es[4*t+1]=v.y; es[4*t+2]=v.z; es[4*t+3]=v.w;
        }
#pragma unroll 8
        for (int j = 0; j < 32; ++j) {
            float a = 0.f;
#pragma unroll
            for (int t = 0; t < 16; ++t) a += es[t] * fcv_w1[t*32 + j];
            hv[j] = silu_f(a * 0.25f);
        }
    }

    const uint4* g = sa4 + p * 385;
    float A[16] = {};

    // ---- v1 path (xs*shs, i = 4p+k) ----
#pragma unroll 1
    for (int k = 0; k < 4; ++k) {
        const float x = nf[4*p + k] * sh_s;
        const uint4* gk = g + k * 64;
#pragma unroll 4
        for (int j = 0; j < 32; ++j) {
            const uint4 a = gk[2*j];
            const uint4 b = gk[2*j + 1];
            const float t = x * hv[j];
            float wv[16]; up8(a, wv); up8(b, wv + 8);
#pragma unroll
            for (int o = 0; o < 16; ++o) A[o] += t*wv[o];
        }
    }

    // ---- v2 path (xv.shv, i = 2p+k), accumulate into the same outputs ----
    const float c3 = 0.57735026918962576f;
#pragma unroll 1
    for (int k = 0; k < 2; ++k) {
        const int i = 2*p + k;
        const float pv = (nf[16+3*i]*s4.y + nf[17+3*i]*s4.z + nf[18+3*i]*s4.w) * c3;
        const uint4* gk = g + 256 + k * 64;
#pragma unroll 4
        for (int j = 0; j < 32; ++j) {
            const uint4 a = gk[2*j];
            const uint4 b = gk[2*j + 1];
            const float t = pv * hv[j];
            float wv[16]; up8(a, wv); up8(b, wv + 8);
#pragma unroll
            for (int o = 0; o < 16; ++o) A[o] += t*wv[o];
        }
    }

#pragma unroll
    for (int o = 0; o < 16; ++o) A[o] = wred4(A[o]);

    if (p == 0 && val) {
        const float cs = 0.03608439182435161f;   // (1/sqrt32)*(1/sqrt24)
        const float sa = sabuf[e];
        const int pos = posbuf[e];
        float4* vp = (float4*)(vbuf + (size_t)pos * 40);
#pragma unroll
        for (int t = 0; t < 4; ++t) {
            float4 r;
            r.x = sa * A[4*t+0] * cs; r.y = sa * A[4*t+1] * cs;
            r.z = sa * A[4*t+2] * cs; r.w = sa * A[4*t+3] * cs;
            vp[t] = r;
        }
    }
}

// ===================== edge_v_b: V vector outputs (cols [384,640)) =====================
// LDS: 4 x 257 uint4 = 16448 B (stride 4112 B, %128==16 -> conflict-free).
// Chunk map: [0,128)=w3 (k*32+j), [128,192)=w4 (k*32+j), [192,256)=w5 (k*32+j).
__global__ __launch_bounds__(BS) void edge_v_b(
    const float* __restrict__ node_ft,
    const int*   __restrict__ ei,
    const float* __restrict__ edge_sh,
    const float* __restrict__ edge_scalars,
    const float* __restrict__ fcv_w1,
    const float* __restrict__ fcv_w2,
    const float* __restrict__ sabuf,
    const int*   __restrict__ posbuf,
    float* __restrict__ vbuf,               // [E,40]
    const int* __restrict__ flag,
    int E)
{
    __shared__ uint4 sb4[4 * 257];          // 16448 B

    const int tid = threadIdx.x;
    for (int idx = tid; idx < 4 * 256; idx += BS) {
        const int p = idx >> 8;
        const int local = idx & 255;
        int j, c0;
        if (local < 128) {                           // w3: i = 4p+k
            const int k = local >> 5; j = local & 31; c0 = 384 + (4*p + k) * 8;
        } else if (local < 192) {                    // w4: i = 2p+k
            const int l = local - 128; const int k = l >> 5; j = l & 31;
            c0 = 512 + (2*p + k) * 8;
        } else {                                     // w5: i = 2p+k
            const int l = local - 192; const int k = l >> 5; j = l & 31;
            c0 = 576 + (2*p + k) * 8;
        }
        const float* src = fcv_w2 + j * 640 + c0;
        sb4[p * 257 + local] = make_uint4(
            pk2(src[0], src[1]), pk2(src[2], src[3]),
            pk2(src[4], src[5]), pk2(src[6], src[7]));
    }

    const int lane = tid & 63;
    const int p = lane >> 4;
    const int q = lane & 15;
    const int w = tid >> 6;
    const int e = blockIdx.x * EPB + w * 16 + q;
    const bool val = (e < E);
    const int ec = val ? e : (E - 1);

    const int is64 = *flag;
    const int snd = is64 ? ei[2*ec] : ei[ec];

    const float4 s4 = *(const float4*)(edge_sh + (size_t)ec * 4);
    const float sh_s = s4.x;
    const float sh_v[3] = {s4.y, s4.z, s4.w};

    const float* nf = node_ft + (size_t)snd * 40;

    __syncthreads();

    float hv[32];
    {
        float es[16];
        const float4* a0 = (const float4*)(edge_scalars + (size_t)ec * 16);
#pragma unroll
        for (int t = 0; t < 4; ++t) {
            const float4 v = a0[t];
            es[4*t+0]=v.x; es[4*t+1]=v.y; es[4*t+2]=v.z; es[4*t+3]=v.w;
        }
#pragma unroll 8
        for (int j = 0; j < 32; ++j) {
            float a = 0.f;
#pragma unroll
            for (int t = 0; t < 16; ++t) a += es[t] * fcv_w1[t*32 + j];
            hv[j] = silu_f(a * 0.25f);
        }
    }

    const uint4* g = sb4 + p * 257;

    // ---- v3 path (xs (x) shv; shv applied after reduction) ----
    float T3[8] = {};
#pragma unroll 1
    for (int k = 0; k < 4; ++k) {
        const float x = nf[4*p + k];
        const uint4* gk = g + k * 32;
#pragma unroll 8
        for (int j = 0; j < 32; ++j) {
            const uint4 a = gk[j];
            const float t = x * hv[j];
            float wv[8]; up8(a, wv);
#pragma unroll
            for (int o = 0; o < 8; ++o) T3[o] += t*wv[o];
        }
    }

    // ---- v4/v5 paths (i = 2p+k); shs & cross folded per-k ----
    float R[24] = {};
    const float c7 = 0.70710678118654752f;
#pragma unroll 1
    for (int k = 0; k < 2; ++k) {
        const int i = 2*p + k;
        const float x0 = nf[16 + 3*i], x1 = nf[17 + 3*i], x2 = nf[18 + 3*i];
        float W4[8] = {}, W5[8] = {};
        const uint4* g4 = g + 128 + k * 32;
        const uint4* g5 = g + 192 + k * 32;
#pragma unroll 8
        for (int j = 0; j < 32; ++j) {
            const uint4 a = g4[j];
            const uint4 b = g5[j];
            const float h = hv[j];
            float wv[8], wu[8]; up8(a, wv); up8(b, wu);
#pragma unroll
            for (int o = 0; o < 8; ++o) {
                W4[o] += h*wv[o];
                W5[o] += h*wu[o];
            }
        }
        const float s0 = sh_s*x0, s1 = sh_s*x1, s2 = sh_s*x2;
        const float cx0 = c7*(x1*sh_v[2] - x2*sh_v[1]);
        const float cx1 = c7*(x2*sh_v[0] - x0*sh_v[2]);
        const float cx2 = c7*(x0*sh_v[1] - x1*sh_v[0]);
#pragma unroll
        for (int o = 0; o < 8; ++o) {
            R[o*3+0] += s0*W4[o] + cx0*W5[o];
            R[o*3+1] += s1*W4[o] + cx1*W5[o];
            R[o*3+2] += s2*W4[o] + cx2*W5[o];
        }
    }

#pragma unroll
    for (int o = 0; o < 8; ++o) T3[o] = wred4(T3[o]);
#pragma unroll
    for (int o = 0; o < 24; ++o) R[o] = wred4(R[o]);

    if (p == 0 && val) {
        const float sc = 0.03125f;               // (1/sqrt32)*(1/sqrt32)
        const float sa = sabuf[e];
        const int pos = posbuf[e];
        float row[24];
#pragma unroll
        for (int o = 0; o < 8; ++o)
#pragma unroll
            for (int c = 0; c < 3; ++c)
                row[o*3+c] = sa * (T3[o]*sh_v[c] + R[o*3+c]) * sc;
        float4* vp = (float4*)(vbuf + (size_t)pos * 40 + 16);
#pragma unroll
        for (int t = 0; t < 6; ++t) {
            float4 r; r.x = row[4*t+0]; r.y = row[4*t+1]; r.z = row[4*t+2]; r.w = row[4*t+3];
            vp[t] = r;
        }
    }
}

__global__ __launch_bounds__(256) void node_reduce(
    const int*   __restrict__ start,
    const float* __restrict__ exbuf,
    const float* __restrict__ vbuf,
    float* __restrict__ out, int N)
{
    const int wave = threadIdx.x >> 6;
    const int lane = threadIdx.x & 63;
    const int n = blockIdx.x * 4 + wave;
    if (n >= N) return;
    const int r0 = start[n], r1 = start[n + 1];
    float z = 0.f, comp = 0.f;
    for (int r = r0; r < r1; ++r) {
        z += exbuf[r];
        if (lane < 40) comp += vbuf[(size_t)r * 40 + lane];
    }
    if (lane < 40)
        out[(size_t)n * 40 + lane] = (z > 0.f) ? comp * rsqrtf(z) : 0.f;
}

extern "C" void kernel_launch(void* const* d_in, const int* in_sizes, int n_in,
                              void* d_out, int out_size, void* d_ws, size_t ws_size,
                              hipStream_t stream) {
    const float* node_ft      = (const float*)d_in[0];
    const int*   edge_index   = (const int*)  d_in[1];
    const float* edge_sh      = (const float*)d_in[2];
    const float* edge_scalars = (const float*)d_in[3];
    const float* w_q_s        = (const float*)d_in[4];
    const float* w_q_v        = (const float*)d_in[5];
    const float* fck_w1       = (const float*)d_in[6];
    const float* fck_w2       = (const float*)d_in[7];
    const float* fcv_w1       = (const float*)d_in[8];
    const float* fcv_w2       = (const float*)d_in[9];
    const float* wdot_s       = (const float*)d_in[10];
    const float* wdot_v       = (const float*)d_in[11];

    const int N = in_sizes[0] / 40;
    const int E = in_sizes[2] / 4;

    float* ws    = (float*)d_ws;
    float* qd    = ws;                               // N*20
    int*   cnt   = (int*)(ws + (size_t)N * 20);      // N
    int*   start = cnt + N;                          // N+1
    int*   curs  = start + N + 1;                    // N
    int*   flg   = curs + N;                         // 1
    size_t off   = (size_t)N * 20 + N + (N + 1) + N + 1;
    off = (off + 3) & ~(size_t)3;                    // 16B align
    float* exbuf  = ws + off;                        // E
    float* sabuf  = exbuf + E;                       // E
    int*   posbuf = (int*)(sabuf + E);               // E
    float* vbuf   = (float*)(posbuf + E);            // E*40 (E%4==0 -> aligned)

    float* out = (float*)d_out;

    const int EB = (E + EPB - 1) / EPB;

    hipLaunchKernelGGL(node_pre, dim3((N + 255) / 256), dim3(256), 0, stream,
                       node_ft, edge_index, w_q_s, w_q_v, wdot_s, wdot_v,
                       qd, cnt, flg, N, E);
    hipLaunchKernelGGL(count_edges, dim3((E + 255) / 256), dim3(256), 0, stream,
                       edge_index, cnt, flg, E);
    hipLaunchKernelGGL(scan_kernel, dim3(1), dim3(1024), 0, stream,
                       cnt, start, curs, N);
    hipLaunchKernelGGL(edge_k, dim3(EB), dim3(BS), 0, stream,
                       node_ft, edge_index, edge_sh, edge_scalars,
                       fck_w1, fck_w2, qd, curs, exbuf, sabuf, posbuf, flg, N, E);
    hipLaunchKernelGGL(edge_v_a, dim3(EB), dim3(BS), 0, stream,
                       node_ft, edge_index, edge_sh, edge_scalars,
                       fcv_w1, fcv_w2, sabuf, posbuf, vbuf, flg, E);
    hipLaunchKernelGGL(edge_v_b, dim3(EB), dim3(BS), 0, stream,
                       node_ft, edge_index, edge_sh, edge_scalars,
                       fcv_w1, fcv_w2, sabuf, posbuf, vbuf, flg, E);
    hipLaunchKernelGGL(node_reduce, dim3((N + 3) / 4), dim3(256), 0, stream,
                       start, exbuf, vbuf, out, N);
}

// Round 5
// 296.407 us; speedup vs baseline: 3.4147x; 1.2497x over previous
//
#include <hip/hip_runtime.h>

// GraphAttention (e3nn-style) on MI355X — Round 9: f16 dot2 weights.
// Round-8 post-mortem: structure healthy (no spill, 0 conflicts, occ 25%),
// edge_k VALU-bound (VALUBusy 67%, 103us). Cost = 1 unpack + 1 FMA per weight
// per edge (~21k ops/edge). Fix: store weights as packed f16 PAIRS in LDS and
// contract with v_dot2_f32_f16 (__builtin_amdgcn_fdot2): 2 products + f32 acc
// per instruction, zero unpack. Factoring out[o] = sum_j h_j*(sum_i x_i W[j,i,o])
// keeps h in f32; w4/w5 contract over j-pairs with h packed f16.
// f16 (10-bit mant) strictly better than previous bf16 (7-bit) weights.
// LDS read count unchanged -> kernels land near the LDS-broadcast floor.
//
// Dims: M0=16 M1=8 Q0=8 Q1=4 O0=16 O1=8 EDGE_BASIS=16 HIDDEN=32
// TPK [32][320]: w1[0,128) w2[128,192) w3[192,256) w4[256,288) w5[288,320)
// TPV [32][640]: w1[0,256) w2[256,384) w3[384,512) w4[512,576) w5[576,640)
//
// Pipeline: node_pre | count_edges | scan | edge_k | edge_v_a | edge_v_b | node_reduce
// ws (4B units): qd[N*20] | cnt[N] | start[N+1] | cursor[N] | flag | pad |
//                exbuf[E] | sabuf[E] | posbuf[E] | vbuf[E*40]

#define BS 256           // threads per block (edge kernels)
#define EPB 64           // edges per block: 4 waves x 16 q-lanes x 1 edge

typedef _Float16 half2_t __attribute__((ext_vector_type(2)));

#ifdef __has_builtin
#if __has_builtin(__builtin_amdgcn_fdot2)
#define USE_FDOT2 1
#endif
#endif

__device__ __forceinline__ float silu_f(float x) {
    return x * (1.0f / (1.0f + __expf(-x)));
}
__device__ __forceinline__ unsigned short f2h(float f) {
    return __builtin_bit_cast(unsigned short, (_Float16)f);
}
__device__ __forceinline__ unsigned pk2h(float a, float b) {   // pack 2 f16
    return (unsigned)f2h(a) | ((unsigned)f2h(b) << 16);
}
__device__ __forceinline__ half2_t uh2(unsigned u) {
    return __builtin_bit_cast(half2_t, u);
}
__device__ __forceinline__ float d2(unsigned a, unsigned b, float c) {
#ifdef USE_FDOT2
    return __builtin_amdgcn_fdot2(uh2(a), uh2(b), c, false);
#else
    const half2_t ha = uh2(a), hb = uh2(b);
    return c + (float)ha[0] * (float)hb[0] + (float)ha[1] * (float)hb[1];
#endif
}
__device__ __forceinline__ float wred4(float v) {          // sum over 4 p-groups
    v += __shfl_xor(v, 16);
    v += __shfl_xor(v, 32);
    return v;
}

__global__ __launch_bounds__(256) void node_pre(
    const float* __restrict__ node_ft,
    const int*   __restrict__ ei,
    const float* __restrict__ w_q_s, const float* __restrict__ w_q_v,
    const float* __restrict__ wdot_s, const float* __restrict__ wdot_v,
    float* __restrict__ qd, int* __restrict__ cnt, int* __restrict__ flag,
    int N, int E)
{
    const int n = blockIdx.x * blockDim.x + threadIdx.x;
    if (n == 0) {
        int acc = 0;
        const int kmax = (E < 64) ? E : 64;
        for (int k = 0; k < kmax; ++k) acc |= ei[2*k + 1];
        *flag = (acc == 0) ? 1 : 0;   // int64 layout => odd words all zero
    }
    if (n >= N) return;
    cnt[n] = 0;

    const float* nf = node_ft + (size_t)n * 40;
    float xs[16];
#pragma unroll
    for (int i = 0; i < 16; ++i) xs[i] = nf[i];
    float q[8];
#pragma unroll
    for (int o = 0; o < 8; ++o) {
        float a = 0.f;
#pragma unroll
        for (int i = 0; i < 16; ++i) a += xs[i] * w_q_s[i*8 + o];
        q[o] = a * 0.25f;
    }
    float* qdn = qd + (size_t)n * 20;
#pragma unroll
    for (int j = 0; j < 8; ++j) {
        float a = 0.f;
#pragma unroll
        for (int i = 0; i < 8; ++i) a += q[i] * wdot_s[i*8 + j];
        qdn[j] = a;
    }
    float xv[8][3];
#pragma unroll
    for (int i = 0; i < 8; ++i)
#pragma unroll
        for (int c = 0; c < 3; ++c) xv[i][c] = nf[16 + i*3 + c];
    float qv[4][3];
#pragma unroll
    for (int o = 0; o < 4; ++o)
#pragma unroll
        for (int c = 0; c < 3; ++c) {
            float a = 0.f;
#pragma unroll
            for (int i = 0; i < 8; ++i) a += xv[i][c] * w_q_v[i*4 + o];
            qv[o][c] = a * 0.35355339059327379f;
        }
#pragma unroll
    for (int j = 0; j < 4; ++j)
#pragma unroll
        for (int c = 0; c < 3; ++c) {
            float a = 0.f;
#pragma unroll
            for (int i = 0; i < 4; ++i) a += qv[i][c] * wdot_v[i*4 + j];
            qdn[8 + j*3 + c] = a;
        }
}

__global__ __launch_bounds__(256) void count_edges(
    const int* __restrict__ ei, int* __restrict__ cnt,
    const int* __restrict__ flag, int E)
{
    const int e = blockIdx.x * blockDim.x + threadIdx.x;
    if (e >= E) return;
    const int is64 = *flag;
    const int rcv = is64 ? ei[2*(E + e)] : ei[E + e];
    atomicAdd(cnt + rcv, 1);
}

// 1 block, 1024 threads; shuffle-based scan (few barriers).
__global__ __launch_bounds__(1024) void scan_kernel(
    const int* __restrict__ cnt, int* __restrict__ start,
    int* __restrict__ cursor, int N)
{
    __shared__ int wsum[16];
    __shared__ int s_carry;
    const int tid = threadIdx.x, wave = tid >> 6, lane = tid & 63;
    if (tid == 0) s_carry = 0;
    __syncthreads();
    for (int base = 0; base < N; base += 1024) {
        const int i = base + tid;
        const int v = (i < N) ? cnt[i] : 0;
        int x = v;                                  // inclusive intra-wave scan
#pragma unroll
        for (int d = 1; d < 64; d <<= 1) {
            const int y = __shfl_up(x, d, 64);
            if (lane >= d) x += y;
        }
        if (lane == 63) wsum[wave] = x;
        __syncthreads();
        if (wave == 0 && lane < 16) {
            int w = wsum[lane];
#pragma unroll
            for (int d = 1; d < 16; d <<= 1) {
                const int y = __shfl_up(w, d, 64);
                if (lane >= d) w += y;              // lanes 16..63 inactive
            }
            wsum[lane] = w;                         // inclusive wave-prefix
        }
        __syncthreads();
        const int woff = (wave == 0) ? 0 : wsum[wave - 1];
        const int carry = s_carry;
        if (i < N) {
            const int s = carry + woff + x - v;     // exclusive
            start[i] = s;
            cursor[i] = s;
        }
        __syncthreads();
        if (tid == 0) s_carry = carry + wsum[15];
        __syncthreads();
    }
    if (tid == 0) start[N] = s_carry;
}

// ===================== edge_k: K-side TP + dot + softmax terms =====================
// LDS: 4 groups x 321 uint4 = 20544 B (group stride 5136 B; %128==16 ->
// 4 concurrent group reads hit disjoint bank quads, conflict-free).
// Per-group uint4 map (f16 pairs):
//  [0,128):  w1  idx j*4 + ip*2 + h   half2=(i0,i0+1), i0=4p+2ip, outs o=4h..4h+3
//  [128,192): w3 idx 128 + j*2 + ip   half2=(i0,i0+1), outs o=0..3
//  [192,256): w2 idx 192 + j*2 + h    half2=(2p,2p+1), outs o=4h..4h+3
//  [256,320): w45 idx 256 + jp*4 + il*2 + h  half2=(j0,j0+1); h=0 -> w4 o0..3,
//             h=1 -> w5 o0..3; i=2p+il
__global__ __launch_bounds__(BS) void edge_k(
    const float* __restrict__ node_ft,
    const int*   __restrict__ ei,
    const float* __restrict__ edge_sh,
    const float* __restrict__ edge_scalars,
    const float* __restrict__ fck_w1,
    const float* __restrict__ fck_w2,
    const float* __restrict__ qd,
    int*   __restrict__ cursor,
    float* __restrict__ exbuf,              // [E] CSR order
    float* __restrict__ sabuf,              // [E] edge order
    int*   __restrict__ posbuf,             // [E] edge order
    const int* __restrict__ flag,
    int N, int E)
{
    __shared__ uint4 sk4[4 * 321];          // 20544 B

    const int tid = threadIdx.x;
    // ---- stage weights (f16 pairs, group-split, permuted) ----
    for (int idx = tid; idx < 4 * 320; idx += BS) {
        const int p = idx / 320;
        const int local = idx - p * 320;
        unsigned r0, r1, r2, r3;
        if (local < 128) {                       // w1: pair over i, 4 outs
            const int j = local >> 2, rr = local & 3, ip = rr >> 1, h = rr & 1;
            const int i0 = 4*p + 2*ip;
            const float* s0 = fck_w2 + j*320 + i0*8 + 4*h;
            const float* s1 = s0 + 8;
            r0 = pk2h(s0[0], s1[0]); r1 = pk2h(s0[1], s1[1]);
            r2 = pk2h(s0[2], s1[2]); r3 = pk2h(s0[3], s1[3]);
        } else if (local < 192) {                // w3: pair over i, 4 outs
            const int l = local - 128; const int j = l >> 1, ip = l & 1;
            const int i0 = 4*p + 2*ip;
            const float* s0 = fck_w2 + j*320 + 192 + i0*4;
            const float* s1 = s0 + 4;
            r0 = pk2h(s0[0], s1[0]); r1 = pk2h(s0[1], s1[1]);
            r2 = pk2h(s0[2], s1[2]); r3 = pk2h(s0[3], s1[3]);
        } else if (local < 256) {                // w2: pair over i=(2p,2p+1)
            const int l = local - 192; const int j = l >> 1, h = l & 1;
            const int i0 = 2*p;
            const float* s0 = fck_w2 + j*320 + 128 + i0*8 + 4*h;
            const float* s1 = s0 + 8;
            r0 = pk2h(s0[0], s1[0]); r1 = pk2h(s0[1], s1[1]);
            r2 = pk2h(s0[2], s1[2]); r3 = pk2h(s0[3], s1[3]);
        } else {                                 // w45: pair over j=(2jp,2jp+1)
            const int l = local - 256; const int jp = l >> 2, rr = l & 3;
            const int il = rr >> 1, h = rr & 1;
            const int i = 2*p + il, j0 = 2*jp;
            const int col = (h == 0 ? 256 : 288) + i*4;
            const float* s0 = fck_w2 + j0*320 + col;
            const float* s1 = s0 + 320;
            r0 = pk2h(s0[0], s1[0]); r1 = pk2h(s0[1], s1[1]);
            r2 = pk2h(s0[2], s1[2]); r3 = pk2h(s0[3], s1[3]);
        }
        sk4[p * 321 + local] = make_uint4(r0, r1, r2, r3);
    }

    const int lane = tid & 63;
    const int p = lane >> 4;
    const int q = lane & 15;
    const int w = tid >> 6;
    const int e = blockIdx.x * EPB + w * 16 + q;
    const bool val = (e < E);
    const int ec = val ? e : (E - 1);

    const int is64 = *flag;
    const int snd = is64 ? ei[2*ec]       : ei[ec];
    const int rcv = is64 ? ei[2*(E + ec)] : ei[E + ec];

    int pos = 0;
    if (p == 0 && val) pos = atomicAdd(cursor + rcv, 1);  // one claimant/edge

    const float4 s4 = *(const float4*)(edge_sh + (size_t)ec * 4);
    const float sh_s = s4.x;
    const float sh_v[3] = {s4.y, s4.z, s4.w};

    const float* nf = node_ft + (size_t)snd * 40;

    __syncthreads();                                 // weights staged; no barriers below

    // ---- hidden activations (per lane; redundant across p) ----
    float hk[32];
    {
        float es[16];
        const float4* a0 = (const float4*)(edge_scalars + (size_t)ec * 16);
#pragma unroll
        for (int t = 0; t < 4; ++t) {
            const float4 v = a0[t];
            es[4*t+0]=v.x; es[4*t+1]=v.y; es[4*t+2]=v.z; es[4*t+3]=v.w;
        }
#pragma unroll 8
        for (int j = 0; j < 32; ++j) {
            float a = 0.f;
#pragma unroll
            for (int t = 0; t < 16; ++t) a += es[t] * fck_w1[t*32 + j];
            hk[j] = silu_f(a * 0.25f);
        }
    }

    const uint4* g = sk4 + p * 321;

    // x packs (f16 pairs of this group's i-quarter)
    const unsigned xs01 = pk2h(nf[4*p + 0], nf[4*p + 1]);
    const unsigned xs23 = pk2h(nf[4*p + 2], nf[4*p + 3]);

    // ---- w1: K1[o] = sum_j h_j * sum_i xs_i W1[j][i][o] ----
    float K1[8] = {};
#pragma unroll 8
    for (int j = 0; j < 32; ++j) {
        const uint4 A = g[j*4+0], B = g[j*4+1], C = g[j*4+2], D = g[j*4+3];
        const float h = hk[j];
        float t;
        t = d2(xs01, A.x, 0.f); t = d2(xs23, C.x, t); K1[0] += h*t;
        t = d2(xs01, A.y, 0.f); t = d2(xs23, C.y, t); K1[1] += h*t;
        t = d2(xs01, A.z, 0.f); t = d2(xs23, C.z, t); K1[2] += h*t;
        t = d2(xs01, A.w, 0.f); t = d2(xs23, C.w, t); K1[3] += h*t;
        t = d2(xs01, B.x, 0.f); t = d2(xs23, D.x, t); K1[4] += h*t;
        t = d2(xs01, B.y, 0.f); t = d2(xs23, D.y, t); K1[5] += h*t;
        t = d2(xs01, B.z, 0.f); t = d2(xs23, D.z, t); K1[6] += h*t;
        t = d2(xs01, B.w, 0.f); t = d2(xs23, D.w, t); K1[7] += h*t;
    }

    // ---- w3 ----
    float K3[4] = {};
#pragma unroll 8
    for (int j = 0; j < 32; ++j) {
        const uint4 Ea = g[128 + j*2], Fb = g[128 + j*2 + 1];
        const float h = hk[j];
        float t;
        t = d2(xs01, Ea.x, 0.f); t = d2(xs23, Fb.x, t); K3[0] += h*t;
        t = d2(xs01, Ea.y, 0.f); t = d2(xs23, Fb.y, t); K3[1] += h*t;
        t = d2(xs01, Ea.z, 0.f); t = d2(xs23, Fb.z, t); K3[2] += h*t;
        t = d2(xs01, Ea.w, 0.f); t = d2(xs23, Fb.w, t); K3[3] += h*t;
    }

    // ---- w2 (vv-dot path; i-pair = 2p,2p+1) ----
    const float c3 = 0.57735026918962576f;
    const float xa0 = nf[16 + 6*p], xa1 = nf[17 + 6*p], xa2 = nf[18 + 6*p];
    const float xb0 = nf[19 + 6*p], xb1 = nf[20 + 6*p], xb2 = nf[21 + 6*p];
    const float pv0 = (xa0*sh_v[0] + xa1*sh_v[1] + xa2*sh_v[2]) * c3;
    const float pv1 = (xb0*sh_v[0] + xb1*sh_v[1] + xb2*sh_v[2]) * c3;
    const unsigned pvp = pk2h(pv0, pv1);
    float K2[8] = {};
#pragma unroll 8
    for (int j = 0; j < 32; ++j) {
        const uint4 U = g[192 + j*2], V = g[192 + j*2 + 1];
        const float h = hk[j];
        K2[0] += h * d2(pvp, U.x, 0.f);
        K2[1] += h * d2(pvp, U.y, 0.f);
        K2[2] += h * d2(pvp, U.z, 0.f);
        K2[3] += h * d2(pvp, U.w, 0.f);
        K2[4] += h * d2(pvp, V.x, 0.f);
        K2[5] += h * d2(pvp, V.y, 0.f);
        K2[6] += h * d2(pvp, V.z, 0.f);
        K2[7] += h * d2(pvp, V.w, 0.f);
    }

    // ---- w4/w5: contract over j-pairs with packed h ----
    float W40[4] = {}, W41[4] = {}, W50[4] = {}, W51[4] = {};
#pragma unroll 4
    for (int jp = 0; jp < 16; ++jp) {
        const unsigned hp = pk2h(hk[2*jp], hk[2*jp+1]);
        const uint4 a = g[256 + jp*4 + 0];   // il0 w4
        const uint4 b = g[256 + jp*4 + 1];   // il0 w5
        const uint4 c = g[256 + jp*4 + 2];   // il1 w4
        const uint4 d = g[256 + jp*4 + 3];   // il1 w5
        W40[0] = d2(hp, a.x, W40[0]); W40[1] = d2(hp, a.y, W40[1]);
        W40[2] = d2(hp, a.z, W40[2]); W40[3] = d2(hp, a.w, W40[3]);
        W50[0] = d2(hp, b.x, W50[0]); W50[1] = d2(hp, b.y, W50[1]);
        W50[2] = d2(hp, b.z, W50[2]); W50[3] = d2(hp, b.w, W50[3]);
        W41[0] = d2(hp, c.x, W41[0]); W41[1] = d2(hp, c.y, W41[1]);
        W41[2] = d2(hp, c.z, W41[2]); W41[3] = d2(hp, c.w, W41[3]);
        W51[0] = d2(hp, d.x, W51[0]); W51[1] = d2(hp, d.y, W51[1]);
        W51[2] = d2(hp, d.z, W51[2]); W51[3] = d2(hp, d.w, W51[3]);
    }

    // epilogue: apply x/sh per i (il = 0,1)
    const float c7 = 0.70710678118654752f;
    float KV[12] = {};
    {
        const float s0 = sh_s*xa0, s1 = sh_s*xa1, s2 = sh_s*xa2;
        const float cx0 = c7*(xa1*sh_v[2] - xa2*sh_v[1]);
        const float cx1 = c7*(xa2*sh_v[0] - xa0*sh_v[2]);
        const float cx2 = c7*(xa0*sh_v[1] - xa1*sh_v[0]);
#pragma unroll
        for (int o = 0; o < 4; ++o) {
            KV[o*3+0] += s0*W40[o] + cx0*W50[o];
            KV[o*3+1] += s1*W40[o] + cx1*W50[o];
            KV[o*3+2] += s2*W40[o] + cx2*W50[o];
        }
    }
    {
        const float s0 = sh_s*xb0, s1 = sh_s*xb1, s2 = sh_s*xb2;
        const float cx0 = c7*(xb1*sh_v[2] - xb2*sh_v[1]);
        const float cx1 = c7*(xb2*sh_v[0] - xb0*sh_v[2]);
        const float cx2 = c7*(xb0*sh_v[1] - xb1*sh_v[0]);
#pragma unroll
        for (int o = 0; o < 4; ++o) {
            KV[o*3+0] += s0*W41[o] + cx0*W51[o];
            KV[o*3+1] += s1*W41[o] + cx1*W51[o];
            KV[o*3+2] += s2*W41[o] + cx2*W51[o];
        }
    }

    // ---- combine partials across the 4 p-groups ----
#pragma unroll
    for (int o = 0; o < 8; ++o) K1[o] = wred4(K1[o]);
#pragma unroll
    for (int o = 0; o < 8; ++o) K2[o] = wred4(K2[o]);
#pragma unroll
    for (int o = 0; o < 4; ++o) K3[o] = wred4(K3[o]);
#pragma unroll
    for (int o = 0; o < 12; ++o) KV[o] = wred4(KV[o]);

    if (p == 0 && val) {
        float qdr[20];
        {
            const float4* rp = (const float4*)(qd + (size_t)rcv * 20);
#pragma unroll
            for (int t = 0; t < 5; ++t) {
                const float4 a = rp[t];
                qdr[4*t+0]=a.x; qdr[4*t+1]=a.y; qdr[4*t+2]=a.z; qdr[4*t+3]=a.w;
            }
        }
        float ds = 0.f;
#pragma unroll
        for (int o = 0; o < 8; ++o) ds += qdr[o] * (sh_s*K1[o] + K2[o]);
        float dv = 0.f;
#pragma unroll
        for (int o = 0; o < 4; ++o)
#pragma unroll
            for (int c = 0; c < 3; ++c)
                dv += qdr[8 + o*3 + c] * (K3[o]*sh_v[c] + KV[o*3+c]);
        const float dot = ds * 4.0343567508008e-3f + dv * 2.0171788261497e-3f;
        const float sa = __expf(0.5f * dot);
        exbuf[pos] = sa*sa; sabuf[e] = sa; posbuf[e] = pos;
    }
}

// ===================== edge_v_a: V scalar outputs (cols [0,384)) =====================
// LDS: 4 x 385 uint4 = 24640 B (stride 6160 B, %128==16 -> conflict-free).
// Per-group uint4 map: [0,256): w1 idx j*8 + ip*4 + h(0..3), half2=(i0,i0+1),
// outs o=4h..; [256,384): w2 idx 256 + j*4 + h, half2=(2p,2p+1).
// shs folded into xs before the single f16 rounding.
__global__ __launch_bounds__(BS) void edge_v_a(
    const float* __restrict__ node_ft,
    const int*   __restrict__ ei,
    const float* __restrict__ edge_sh,
    const float* __restrict__ edge_scalars,
    const float* __restrict__ fcv_w1,
    const float* __restrict__ fcv_w2,
    const float* __restrict__ sabuf,
    const int*   __restrict__ posbuf,
    float* __restrict__ vbuf,               // [E,40]
    const int* __restrict__ flag,
    int E)
{
    __shared__ uint4 sa4[4 * 385];          // 24640 B

    const int tid = threadIdx.x;
    for (int idx = tid; idx < 4 * 384; idx += BS) {
        const int p = idx / 384;
        const int local = idx - p * 384;
        const float* s0;
        const float* s1;
        if (local < 256) {                           // w1
            const int j = local >> 3, rr = local & 7, ip = rr >> 2, h = rr & 3;
            const int i0 = 4*p + 2*ip;
            s0 = fcv_w2 + j*640 + i0*16 + h*4;
            s1 = s0 + 16;
        } else {                                     // w2
            const int l = local - 256; const int j = l >> 2, h = l & 3;
            const int i0 = 2*p;
            s0 = fcv_w2 + j*640 + 256 + i0*16 + h*4;
            s1 = s0 + 16;
        }
        sa4[p * 385 + local] = make_uint4(
            pk2h(s0[0], s1[0]), pk2h(s0[1], s1[1]),
            pk2h(s0[2], s1[2]), pk2h(s0[3], s1[3]));
    }

    const int lane = tid & 63;
    const int p = lane >> 4;
    const int q = lane & 15;
    const int w = tid >> 6;
    const int e = blockIdx.x * EPB + w * 16 + q;
    const bool val = (e < E);
    const int ec = val ? e : (E - 1);

    const int is64 = *flag;
    const int snd = is64 ? ei[2*ec] : ei[ec];

    const float4 s4 = *(const float4*)(edge_sh + (size_t)ec * 4);
    const float sh_s = s4.x;

    const float* nf = node_ft + (size_t)snd * 40;

    __syncthreads();

    float hv[32];
    {
        float es[16];
        const float4* a0 = (const float4*)(edge_scalars + (size_t)ec * 16);
#pragma unroll
        for (int t = 0; t < 4; ++t) {
            const float4 v = a0[t];
            es[4*t+0]=v.x; es[4*t+1]=v.y; es[4*t+2]=v.z; es[4*t+3]=v.w;
        }
#pragma unroll 8
        for (int j = 0; j < 32; ++j) {
            float a = 0.f;
#pragma unroll
            for (int t = 0; t < 16; ++t) a += es[t] * fcv_w1[t*32 + j];
            hv[j] = silu_f(a * 0.25f);
        }
    }

    const uint4* g = sa4 + p * 385;

    // packs: shs folded into xs; pv for w2
    const unsigned xs01 = pk2h(nf[4*p + 0]*sh_s, nf[4*p + 1]*sh_s);
    const unsigned xs23 = pk2h(nf[4*p + 2]*sh_s, nf[4*p + 3]*sh_s);
    const float c3 = 0.57735026918962576f;
    const float pv0 = (nf[16+6*p]*s4.y + nf[17+6*p]*s4.z + nf[18+6*p]*s4.w) * c3;
    const float pv1 = (nf[19+6*p]*s4.y + nf[20+6*p]*s4.z + nf[21+6*p]*s4.w) * c3;
    const unsigned pvp = pk2h(pv0, pv1);

    float A[16] = {};

    // ---- w1 path ----
#pragma unroll 2
    for (int j = 0; j < 32; ++j) {
        const uint4* gw = g + j*8;
        const uint4 a0 = gw[0], a1 = gw[1], a2 = gw[2], a3 = gw[3];   // ip0
        const uint4 b0 = gw[4], b1 = gw[5], b2 = gw[6], b3 = gw[7];   // ip1
        const float h = hv[j];
        float t;
        t = d2(xs01, a0.x, 0.f); t = d2(xs23, b0.x, t); A[0]  += h*t;
        t = d2(xs01, a0.y, 0.f); t = d2(xs23, b0.y, t); A[1]  += h*t;
        t = d2(xs01, a0.z, 0.f); t = d2(xs23, b0.z, t); A[2]  += h*t;
        t = d2(xs01, a0.w, 0.f); t = d2(xs23, b0.w, t); A[3]  += h*t;
        t = d2(xs01, a1.x, 0.f); t = d2(xs23, b1.x, t); A[4]  += h*t;
        t = d2(xs01, a1.y, 0.f); t = d2(xs23, b1.y, t); A[5]  += h*t;
        t = d2(xs01, a1.z, 0.f); t = d2(xs23, b1.z, t); A[6]  += h*t;
        t = d2(xs01, a1.w, 0.f); t = d2(xs23, b1.w, t); A[7]  += h*t;
        t = d2(xs01, a2.x, 0.f); t = d2(xs23, b2.x, t); A[8]  += h*t;
        t = d2(xs01, a2.y, 0.f); t = d2(xs23, b2.y, t); A[9]  += h*t;
        t = d2(xs01, a2.z, 0.f); t = d2(xs23, b2.z, t); A[10] += h*t;
        t = d2(xs01, a2.w, 0.f); t = d2(xs23, b2.w, t); A[11] += h*t;
        t = d2(xs01, a3.x, 0.f); t = d2(xs23, b3.x, t); A[12] += h*t;
        t = d2(xs01, a3.y, 0.f); t = d2(xs23, b3.y, t); A[13] += h*t;
        t = d2(xs01, a3.z, 0.f); t = d2(xs23, b3.z, t); A[14] += h*t;
        t = d2(xs01, a3.w, 0.f); t = d2(xs23, b3.w, t); A[15] += h*t;
    }

    // ---- w2 path ----
#pragma unroll 4
    for (int j = 0; j < 32; ++j) {
        const uint4* gw = g + 256 + j*4;
        const uint4 u0 = gw[0], u1 = gw[1], u2 = gw[2], u3 = gw[3];
        const float h = hv[j];
        A[0]  += h * d2(pvp, u0.x, 0.f);
        A[1]  += h * d2(pvp, u0.y, 0.f);
        A[2]  += h * d2(pvp, u0.z, 0.f);
        A[3]  += h * d2(pvp, u0.w, 0.f);
        A[4]  += h * d2(pvp, u1.x, 0.f);
        A[5]  += h * d2(pvp, u1.y, 0.f);
        A[6]  += h * d2(pvp, u1.z, 0.f);
        A[7]  += h * d2(pvp, u1.w, 0.f);
        A[8]  += h * d2(pvp, u2.x, 0.f);
        A[9]  += h * d2(pvp, u2.y, 0.f);
        A[10] += h * d2(pvp, u2.z, 0.f);
        A[11] += h * d2(pvp, u2.w, 0.f);
        A[12] += h * d2(pvp, u3.x, 0.f);
        A[13] += h * d2(pvp, u3.y, 0.f);
        A[14] += h * d2(pvp, u3.z, 0.f);
        A[15] += h * d2(pvp, u3.w, 0.f);
    }

#pragma unroll
    for (int o = 0; o < 16; ++o) A[o] = wred4(A[o]);

    if (p == 0 && val) {
        const float cs = 0.03608439182435161f;   // (1/sqrt32)*(1/sqrt24)
        const float sa = sabuf[e];
        const int pos = posbuf[e];
        float4* vp = (float4*)(vbuf + (size_t)pos * 40);
#pragma unroll
        for (int t = 0; t < 4; ++t) {
            float4 r;
            r.x = sa * A[4*t+0] * cs; r.y = sa * A[4*t+1] * cs;
            r.z = sa * A[4*t+2] * cs; r.w = sa * A[4*t+3] * cs;
            vp[t] = r;
        }
    }
}

// ===================== edge_v_b: V vector outputs (cols [384,640)) =====================
// LDS: 4 x 257 uint4 = 16448 B (stride 4112 B, %128==16 -> conflict-free).
// Per-group uint4 map: [0,128): w3 idx j*4 + ip*2 + h, half2=(i0,i0+1), o=4h..;
// [128,256): w45 idx 128 + (jp*2+il)*4 + h2, half2=(j0,j0+1); h2<2 -> w4, else w5,
// o0=(h2&1)*4; i=2p+il.
__global__ __launch_bounds__(BS) void edge_v_b(
    const float* __restrict__ node_ft,
    const int*   __restrict__ ei,
    const float* __restrict__ edge_sh,
    const float* __restrict__ edge_scalars,
    const float* __restrict__ fcv_w1,
    const float* __restrict__ fcv_w2,
    const float* __restrict__ sabuf,
    const int*   __restrict__ posbuf,
    float* __restrict__ vbuf,               // [E,40]
    const int* __restrict__ flag,
    int E)
{
    __shared__ uint4 sb4[4 * 257];          // 16448 B

    const int tid = threadIdx.x;
    for (int idx = tid; idx < 4 * 256; idx += BS) {
        const int p = idx >> 8;
        const int local = idx & 255;
        const float* s0;
        const float* s1;
        if (local < 128) {                           // w3: pair over i
            const int j = local >> 2, rr = local & 3, ip = rr >> 1, h = rr & 1;
            const int i0 = 4*p + 2*ip;
            s0 = fcv_w2 + j*640 + 384 + i0*8 + 4*h;
            s1 = s0 + 8;
        } else {                                     // w45: pair over j
            const int l = local - 128;
            const int jp = l >> 3, rr = l & 7, il = rr >> 2, h2 = rr & 3;
            const int i = 2*p + il, j0 = 2*jp;
            const int base = (h2 < 2) ? 512 : 576;
            s0 = fcv_w2 + j0*640 + base + i*8 + (h2 & 1)*4;
            s1 = s0 + 640;
        }
        sb4[p * 257 + local] = make_uint4(
            pk2h(s0[0], s1[0]), pk2h(s0[1], s1[1]),
            pk2h(s0[2], s1[2]), pk2h(s0[3], s1[3]));
    }

    const int lane = tid & 63;
    const int p = lane >> 4;
    const int q = lane & 15;
    const int w = tid >> 6;
    const int e = blockIdx.x * EPB + w * 16 + q;
    const bool val = (e < E);
    const int ec = val ? e : (E - 1);

    const int is64 = *flag;
    const int snd = is64 ? ei[2*ec] : ei[ec];

    const float4 s4 = *(const float4*)(edge_sh + (size_t)ec * 4);
    const float sh_s = s4.x;
    const float sh_v[3] = {s4.y, s4.z, s4.w};

    const float* nf = node_ft + (size_t)snd * 40;

    __syncthreads();

    float hv[32];
    {
        float es[16];
        const float4* a0 = (const float4*)(edge_scalars + (size_t)ec * 16);
#pragma unroll
        for (int t = 0; t < 4; ++t) {
            const float4 v = a0[t];
            es[4*t+0]=v.x; es[4*t+1]=v.y; es[4*t+2]=v.z; es[4*t+3]=v.w;
        }
#pragma unroll 8
        for (int j = 0; j < 32; ++j) {
            float a = 0.f;
#pragma unroll
            for (int t = 0; t < 16; ++t) a += es[t] * fcv_w1[t*32 + j];
            hv[j] = silu_f(a * 0.25f);
        }
    }

    const uint4* g = sb4 + p * 257;

    const unsigned xs01 = pk2h(nf[4*p + 0], nf[4*p + 1]);
    const unsigned xs23 = pk2h(nf[4*p + 2], nf[4*p + 3]);

    // ---- w3 path (xs (x) shv; shv applied after reduction) ----
    float T3[8] = {};
#pragma unroll 4
    for (int j = 0; j < 32; ++j) {
        const uint4 E0 = g[j*4+0], E1 = g[j*4+1];   // ip0: o0..3, o4..7
        const uint4 F0 = g[j*4+2], F1 = g[j*4+3];   // ip1
        const float h = hv[j];
        float t;
        t = d2(xs01, E0.x, 0.f); t = d2(xs23, F0.x, t); T3[0] += h*t;
        t = d2(xs01, E0.y, 0.f); t = d2(xs23, F0.y, t); T3[1] += h*t;
        t = d2(xs01, E0.z, 0.f); t = d2(xs23, F0.z, t); T3[2] += h*t;
        t = d2(xs01, E0.w, 0.f); t = d2(xs23, F0.w, t); T3[3] += h*t;
        t = d2(xs01, E1.x, 0.f); t = d2(xs23, F1.x, t); T3[4] += h*t;
        t = d2(xs01, E1.y, 0.f); t = d2(xs23, F1.y, t); T3[5] += h*t;
        t = d2(xs01, E1.z, 0.f); t = d2(xs23, F1.z, t); T3[6] += h*t;
        t = d2(xs01, E1.w, 0.f); t = d2(xs23, F1.w, t); T3[7] += h*t;
    }

    // ---- w4/w5: contract over j-pairs with packed h ----
    float W40[8] = {}, W41[8] = {}, W50[8] = {}, W51[8] = {};
#pragma unroll 2
    for (int jp = 0; jp < 16; ++jp) {
        const unsigned hp = pk2h(hv[2*jp], hv[2*jp+1]);
        const uint4* gw = g + 128 + jp*8;
        const uint4 a = gw[0], b = gw[1], c = gw[2], d = gw[3];   // il0: w4 lo,hi; w5 lo,hi
        const uint4 e2 = gw[4], f = gw[5], m = gw[6], n = gw[7];  // il1
        W40[0] = d2(hp, a.x, W40[0]); W40[1] = d2(hp, a.y, W40[1]);
        W40[2] = d2(hp, a.z, W40[2]); W40[3] = d2(hp, a.w, W40[3]);
        W40[4] = d2(hp, b.x, W40[4]); W40[5] = d2(hp, b.y, W40[5]);
        W40[6] = d2(hp, b.z, W40[6]); W40[7] = d2(hp, b.w, W40[7]);
        W50[0] = d2(hp, c.x, W50[0]); W50[1] = d2(hp, c.y, W50[1]);
        W50[2] = d2(hp, c.z, W50[2]); W50[3] = d2(hp, c.w, W50[3]);
        W50[4] = d2(hp, d.x, W50[4]); W50[5] = d2(hp, d.y, W50[5]);
        W50[6] = d2(hp, d.z, W50[6]); W50[7] = d2(hp, d.w, W50[7]);
        W41[0] = d2(hp, e2.x, W41[0]); W41[1] = d2(hp, e2.y, W41[1]);
        W41[2] = d2(hp, e2.z, W41[2]); W41[3] = d2(hp, e2.w, W41[3]);
        W41[4] = d2(hp, f.x, W41[4]); W41[5] = d2(hp, f.y, W41[5]);
        W41[6] = d2(hp, f.z, W41[6]); W41[7] = d2(hp, f.w, W41[7]);
        W51[0] = d2(hp, m.x, W51[0]); W51[1] = d2(hp, m.y, W51[1]);
        W51[2] = d2(hp, m.z, W51[2]); W51[3] = d2(hp, m.w, W51[3]);
        W51[4] = d2(hp, n.x, W51[4]); W51[5] = d2(hp, n.y, W51[5]);
        W51[6] = d2(hp, n.z, W51[6]); W51[7] = d2(hp, n.w, W51[7]);
    }

    // epilogue: apply x/sh per i (il = 0,1)
    const float c7 = 0.70710678118654752f;
    float R[24] = {};
    {
        const float x0 = nf[16 + 6*p], x1 = nf[17 + 6*p], x2 = nf[18 + 6*p];
        const float s0 = sh_s*x0, s1 = sh_s*x1, s2 = sh_s*x2;
        const float cx0 = c7*(x1*sh_v[2] - x2*sh_v[1]);
        const float cx1 = c7*(x2*sh_v[0] - x0*sh_v[2]);
        const float cx2 = c7*(x0*sh_v[1] - x1*sh_v[0]);
#pragma unroll
        for (int o = 0; o < 8; ++o) {
            R[o*3+0] += s0*W40[o] + cx0*W50[o];
            R[o*3+1] += s1*W40[o] + cx1*W50[o];
            R[o*3+2] += s2*W40[o] + cx2*W50[o];
        }
    }
    {
        const float x0 = nf[19 + 6*p], x1 = nf[20 + 6*p], x2 = nf[21 + 6*p];
        const float s0 = sh_s*x0, s1 = sh_s*x1, s2 = sh_s*x2;
        const float cx0 = c7*(x1*sh_v[2] - x2*sh_v[1]);
        const float cx1 = c7*(x2*sh_v[0] - x0*sh_v[2]);
        const float cx2 = c7*(x0*sh_v[1] - x1*sh_v[0]);
#pragma unroll
        for (int o = 0; o < 8; ++o) {
            R[o*3+0] += s0*W41[o] + cx0*W51[o];
            R[o*3+1] += s1*W41[o] + cx1*W51[o];
            R[o*3+2] += s2*W41[o] + cx2*W51[o];
        }
    }

#pragma unroll
    for (int o = 0; o < 8; ++o) T3[o] = wred4(T3[o]);
#pragma unroll
    for (int o = 0; o < 24; ++o) R[o] = wred4(R[o]);

    if (p == 0 && val) {
        const float sc = 0.03125f;               // (1/sqrt32)*(1/sqrt32)
        const float sa = sabuf[e];
        const int pos = posbuf[e];
        float row[24];
#pragma unroll
        for (int o = 0; o < 8; ++o)
#pragma unroll
            for (int c = 0; c < 3; ++c)
                row[o*3+c] = sa * (T3[o]*sh_v[c] + R[o*3+c]) * sc;
        float4* vp = (float4*)(vbuf + (size_t)pos * 40 + 16);
#pragma unroll
        for (int t = 0; t < 6; ++t) {
            float4 r; r.x = row[4*t+0]; r.y = row[4*t+1]; r.z = row[4*t+2]; r.w = row[4*t+3];
            vp[t] = r;
        }
    }
}

__global__ __launch_bounds__(256) void node_reduce(
    const int*   __restrict__ start,
    const float* __restrict__ exbuf,
    const float* __restrict__ vbuf,
    float* __restrict__ out, int N)
{
    const int wave = threadIdx.x >> 6;
    const int lane = threadIdx.x & 63;
    const int n = blockIdx.x * 4 + wave;
    if (n >= N) return;
    const int r0 = start[n], r1 = start[n + 1];
    float z = 0.f, comp = 0.f;
    for (int r = r0; r < r1; ++r) {
        z += exbuf[r];
        if (lane < 40) comp += vbuf[(size_t)r * 40 + lane];
    }
    if (lane < 40)
        out[(size_t)n * 40 + lane] = (z > 0.f) ? comp * rsqrtf(z) : 0.f;
}

extern "C" void kernel_launch(void* const* d_in, const int* in_sizes, int n_in,
                              void* d_out, int out_size, void* d_ws, size_t ws_size,
                              hipStream_t stream) {
    const float* node_ft      = (const float*)d_in[0];
    const int*   edge_index   = (const int*)  d_in[1];
    const float* edge_sh      = (const float*)d_in[2];
    const float* edge_scalars = (const float*)d_in[3];
    const float* w_q_s        = (const float*)d_in[4];
    const float* w_q_v        = (const float*)d_in[5];
    const float* fck_w1       = (const float*)d_in[6];
    const float* fck_w2       = (const float*)d_in[7];
    const float* fcv_w1       = (const float*)d_in[8];
    const float* fcv_w2       = (const float*)d_in[9];
    const float* wdot_s       = (const float*)d_in[10];
    const float* wdot_v       = (const float*)d_in[11];

    const int N = in_sizes[0] / 40;
    const int E = in_sizes[2] / 4;

    float* ws    = (float*)d_ws;
    float* qd    = ws;                               // N*20
    int*   cnt   = (int*)(ws + (size_t)N * 20);      // N
    int*   start = cnt + N;                          // N+1
    int*   curs  = start + N + 1;                    // N
    int*   flg   = curs + N;                         // 1
    size_t off   = (size_t)N * 20 + N + (N + 1) + N + 1;
    off = (off + 3) & ~(size_t)3;                    // 16B align
    float* exbuf  = ws + off;                        // E
    float* sabuf  = exbuf + E;                       // E
    int*   posbuf = (int*)(sabuf + E);               // E
    float* vbuf   = (float*)(posbuf + E);            // E*40 (E%4==0 -> aligned)

    float* out = (float*)d_out;

    const int EB = (E + EPB - 1) / EPB;

    hipLaunchKernelGGL(node_pre, dim3((N + 255) / 256), dim3(256), 0, stream,
                       node_ft, edge_index, w_q_s, w_q_v, wdot_s, wdot_v,
                       qd, cnt, flg, N, E);
    hipLaunchKernelGGL(count_edges, dim3((E + 255) / 256), dim3(256), 0, stream,
                       edge_index, cnt, flg, E);
    hipLaunchKernelGGL(scan_kernel, dim3(1), dim3(1024), 0, stream,
                       cnt, start, curs, N);
    hipLaunchKernelGGL(edge_k, dim3(EB), dim3(BS), 0, stream,
                       node_ft, edge_index, edge_sh, edge_scalars,
                       fck_w1, fck_w2, qd, curs, exbuf, sabuf, posbuf, flg, N, E);
    hipLaunchKernelGGL(edge_v_a, dim3(EB), dim3(BS), 0, stream,
                       node_ft, edge_index, edge_sh, edge_scalars,
                       fcv_w1, fcv_w2, sabuf, posbuf, vbuf, flg, E);
    hipLaunchKernelGGL(edge_v_b, dim3(EB), dim3(BS), 0, stream,
                       node_ft, edge_index, edge_sh, edge_scalars,
                       fcv_w1, fcv_w2, sabuf, posbuf, vbuf, flg, E);
    hipLaunchKernelGGL(node_reduce, dim3((N + 3) / 4), dim3(256), 0, stream,
                       start, exbuf, vbuf, out, N);
}